// Round 1
// baseline (470.717 us; speedup 1.0000x reference)
//
#include <hip/hip_runtime.h>
#include <float.h>
#include <limits.h>

// Codebook / VQ: x [65536][256] fp32, codes [1024][256] fp32
// out: quantized [65536][256] fp32, then indices [65536] as fp32 values.
// Tiered: fp16 MFMA GEMM argmin (all rows) -> fp32 rescue (gap<EPS1 rows)
//        -> fp64+DELTA smallest-index rescue (gap<EPS2 rows, proven round 5).
// This round: 64-row blocks (4 blocks/CU, 4 waves/SIMD), packed u32 keys
// (truncated score | index) with min-network top-2, shfl-butterfly reduction
// (kills the 32-way sm1[tid*32+t] bank conflict).
#define D     256
#define C     1024
#define EPS1  0.45f     // fp16-MFMA gap flag: 0.3 (fp16 err margin) + 0.125 (10-bit key truncation) + slack
#define EPS2  0.02f     // fp32 gap flag (proven)
#define DELTA 1.0e-4    // np ulp-collision window on exact fp64 distances
#define BR    16        // rows per batch in fp32 rescue

typedef _Float16 half8 __attribute__((ext_vector_type(8)));
typedef _Float16 half4_t __attribute__((ext_vector_type(4)));
typedef float v4f __attribute__((ext_vector_type(4)));

static __device__ __forceinline__ unsigned umin_(unsigned a, unsigned b) { return a < b ? a : b; }
static __device__ __forceinline__ unsigned umax_(unsigned a, unsigned b) { return a > b ? a : b; }

// prep: cnorm fp32, codes -> fp16 copy, codes -> fp32 transpose, zero counters
__global__ __launch_bounds__(256)
void prep(const float* __restrict__ codes, float* __restrict__ cnorm,
          _Float16* __restrict__ codes_h, float* __restrict__ codes_t,
          int* __restrict__ count1, int* __restrict__ count2) {
    if (blockIdx.x == 0 && threadIdx.x == 0) { *count1 = 0; *count2 = 0; }
    int wave = (blockIdx.x * blockDim.x + threadIdx.x) >> 6;   // 0..1023, one per code
    int lane = threadIdx.x & 63;
    float4 v = ((const float4*)(codes + (size_t)wave * D))[lane];
    // fp16 copy (k-contiguous, same layout)
    half4_t h; h[0] = (_Float16)v.x; h[1] = (_Float16)v.y; h[2] = (_Float16)v.z; h[3] = (_Float16)v.w;
    *(half4_t*)(codes_h + (size_t)wave * D + 4 * lane) = h;
    // fp32 transpose codes_t[k][c]
    codes_t[(size_t)(4*lane+0) * C + wave] = v.x;
    codes_t[(size_t)(4*lane+1) * C + wave] = v.y;
    codes_t[(size_t)(4*lane+2) * C + wave] = v.z;
    codes_t[(size_t)(4*lane+3) * C + wave] = v.w;
    float s = v.x * v.x + v.y * v.y + v.z * v.z + v.w * v.w;
    #pragma unroll
    for (int off = 32; off >= 1; off >>= 1) s += __shfl_xor(s, off, 64);
    if (lane == 0) cnorm[wave] = s;
}

// ---- main: fp16 MFMA distance argmin, 64 rows/block, code-split across 4 waves ----
// Packed key: scores shifted +1024 (always positive for this data => IEEE bits
// order as uints), low 10 mantissa bits replaced by code index => u32 min is a
// lexicographic (trunc score, index) compare. Truncation error < 0.125 absorbed
// into EPS1.
#define LDA 264   // fp16 leading dim of x-tile (pad 8 halves; 16B-chunk stride odd)
__global__ __launch_bounds__(256, 4)
void codebook_mfma(const float* __restrict__ x, const _Float16* __restrict__ codes_h,
                   const float* __restrict__ codes, const float* __restrict__ cnorm,
                   float* __restrict__ out_q, float* __restrict__ out_i,
                   int* __restrict__ count1, int* __restrict__ rowlist1) {
    __shared__ __align__(16) _Float16 Ah[64 * LDA];   // 33792 B
    __shared__ uint2 red[64][4];                      // 2048 B: per-(row,wave) top-2 keys
    __shared__ int win[64];

    const int tid  = threadIdx.x;
    const int w    = tid >> 6, lane = tid & 63;
    const int quad = lane >> 4, l15 = lane & 15;
    const int row0 = blockIdx.x * 64;

    // stage x-tile fp32 -> fp16 LDS [64][LDA]
    #pragma unroll
    for (int p = 0; p < 16; ++p) {
        int flat = p * 256 + tid;          // 0..4095
        int r = flat >> 6, q = flat & 63;  // row, float4-idx
        float4 v = ((const float4*)x)[(size_t)(row0 + r) * 64 + q];
        half4_t h; h[0]=(_Float16)v.x; h[1]=(_Float16)v.y; h[2]=(_Float16)v.z; h[3]=(_Float16)v.w;
        *(half4_t*)(Ah + r * LDA + 4 * q) = h;
    }
    __syncthreads();

    // per-lane top-2 packed keys over 16 rows; row = ra*16 + quad*4 + reg
    unsigned K1[16], K2[16];
    #pragma unroll
    for (int i = 0; i < 16; ++i) { K1[i] = 0xFFFFFFFFu; K2[i] = 0xFFFFFFFFu; }

    // wave w covers codes [w*256, w*256+256) in 4 chunks of 64
    for (int ct = 0; ct < 4; ++ct) {
        v4f acc[4][4];
        #pragma unroll
        for (int ra = 0; ra < 4; ++ra)
            #pragma unroll
            for (int jb = 0; jb < 4; ++jb)
                acc[ra][jb] = (v4f){0.f, 0.f, 0.f, 0.f};

        const int c0 = w * 256 + ct * 64;
        const _Float16* bbase = codes_h + (size_t)(c0 + l15) * D + quad * 8;
        #pragma unroll
        for (int kc = 0; kc < 8; ++kc) {
            half8 bf[4], af[4];
            #pragma unroll
            for (int jb = 0; jb < 4; ++jb)
                bf[jb] = *(const half8*)(bbase + jb * (16 * D) + kc * 32);
            #pragma unroll
            for (int ra = 0; ra < 4; ++ra)
                af[ra] = *(const half8*)(Ah + (ra*16 + l15) * LDA + kc*32 + quad*8);
            #pragma unroll
            for (int ra = 0; ra < 4; ++ra)
                #pragma unroll
                for (int jb = 0; jb < 4; ++jb)
                    acc[ra][jb] = __builtin_amdgcn_mfma_f32_16x16x32_f16(af[ra], bf[jb], acc[ra][jb], 0, 0, 0);
        }

        // score = (cnorm + 1024) - 2*dot  (positive); pack + top-2 network
        float cnf[4]; int colc[4];
        #pragma unroll
        for (int jb = 0; jb < 4; ++jb) {
            colc[jb] = c0 + jb*16 + l15;
            cnf[jb]  = cnorm[colc[jb]] + 1024.0f;
        }
        #pragma unroll
        for (int ra = 0; ra < 4; ++ra)
            #pragma unroll
            for (int reg = 0; reg < 4; ++reg) {
                const int m = ra * 4 + reg;
                unsigned k0 = (__float_as_uint(fmaf(-2.0f, acc[ra][0][reg], cnf[0])) & 0xFFFFFC00u) | (unsigned)colc[0];
                unsigned k1 = (__float_as_uint(fmaf(-2.0f, acc[ra][1][reg], cnf[1])) & 0xFFFFFC00u) | (unsigned)colc[1];
                unsigned k2 = (__float_as_uint(fmaf(-2.0f, acc[ra][2][reg], cnf[2])) & 0xFFFFFC00u) | (unsigned)colc[2];
                unsigned k3 = (__float_as_uint(fmaf(-2.0f, acc[ra][3][reg], cnf[3])) & 0xFFFFFC00u) | (unsigned)colc[3];
                unsigned lo01 = umin_(k0, k1), hi01 = umax_(k0, k1);
                unsigned lo23 = umin_(k2, k3), hi23 = umax_(k2, k3);
                unsigned best = umin_(lo01, lo23);
                unsigned mid  = umax_(lo01, lo23);
                unsigned sec  = umin_(umin_(hi01, hi23), mid);
                unsigned t    = umax_(K1[m], best);
                K2[m] = umin_(umin_(K2[m], sec), t);
                K1[m] = umin_(K1[m], best);
            }
    }

    // wave-internal merge across the 16 lanes (same quad group) holding the
    // row's candidates: butterfly over l15 (masks < 16 stay in-group)
    #pragma unroll
    for (int m = 0; m < 16; ++m) {
        #pragma unroll
        for (int off = 1; off < 16; off <<= 1) {
            unsigned o1 = (unsigned)__shfl_xor((int)K1[m], off, 64);
            unsigned o2 = (unsigned)__shfl_xor((int)K2[m], off, 64);
            unsigned t  = umax_(K1[m], o1);
            K2[m] = umin_(umin_(K2[m], o2), t);
            K1[m] = umin_(K1[m], o1);
        }
    }
    if (l15 == 0) {
        #pragma unroll
        for (int m = 0; m < 16; ++m) {
            int row = (m >> 2) * 16 + quad * 4 + (m & 3);
            red[row][w] = make_uint2(K1[m], K2[m]);
        }
    }
    __syncthreads();

    // cross-wave merge (4 waves), final winner + gap flag
    if (tid < 64) {
        unsigned b1 = red[tid][0].x, b2 = red[tid][0].y;
        #pragma unroll
        for (int ww = 1; ww < 4; ++ww) {
            unsigned o1 = red[tid][ww].x, o2 = red[tid][ww].y;
            unsigned t  = umax_(b1, o1);
            b2 = umin_(umin_(b2, o2), t);
            b1 = umin_(b1, o1);
        }
        int bi = (int)(b1 & 0x3FFu);
        win[tid] = bi;
        out_i[row0 + tid] = (float)bi;
        float g1 = __uint_as_float(b1 & 0xFFFFFC00u);
        float g2 = __uint_as_float(b2 & 0xFFFFFC00u);
        if (g2 - g1 < EPS1) {
            int s = atomicAdd(count1, 1);
            rowlist1[s] = row0 + tid;
        }
    }
    __syncthreads();

    // gather quantized rows (flagged rows overwritten by rescues later)
    #pragma unroll
    for (int p = 0; p < 16; ++p) {
        int flat = p * 256 + tid;
        int r = flat >> 6, q = flat & 63;
        float4 v = ((const float4*)codes)[(size_t)win[r] * 64 + q];
        ((float4*)out_q)[(size_t)(row0 + r) * 64 + q] = v;
    }
}

// ---- tier-1: fp32 rescore of flagged rows, BR rows/block share codes stream ----
__global__ __launch_bounds__(256)
void rescue32(const float* __restrict__ x, const float* __restrict__ codes,
              const float* __restrict__ codes_t, const float* __restrict__ cnorm,
              const int* __restrict__ count1, const int* __restrict__ rowlist1,
              float* __restrict__ out_q, float* __restrict__ out_i,
              int* __restrict__ count2, int* __restrict__ rowlist2) {
    __shared__ __align__(16) float xr[BR * D];   // 16 KB
    __shared__ int rows_s[BR];
    __shared__ int winc_s[BR];
    __shared__ float wm1[4], wm2[4];
    __shared__ int wi_[4];
    const int t = threadIdx.x;
    const int n1 = *count1;
    if (n1 == 0) return;
    const int nb = (n1 + BR - 1) / BR;
    const float4* ct4 = (const float4*)codes_t;  // [k][c/4]

    for (int b = blockIdx.x; b < nb; b += gridDim.x) {
        __syncthreads();
        if (t < BR) {
            int idx = b * BR + t;
            if (idx >= n1) idx = n1 - 1;           // duplicate tail rows (benign)
            rows_s[t] = rowlist1[idx];
        }
        __syncthreads();
        #pragma unroll
        for (int p = 0; p < BR * 64 / 256; ++p) {  // 4 iters
            int flat = p * 256 + t;
            int r = flat >> 6, q = flat & 63;
            ((float4*)xr)[r * 64 + q] = ((const float4*)x)[(size_t)rows_s[r] * 64 + q];
        }
        __syncthreads();

        float acc[BR][4];
        #pragma unroll
        for (int r = 0; r < BR; ++r)
            #pragma unroll
            for (int j = 0; j < 4; ++j) acc[r][j] = 0.f;

        for (int k = 0; k < D; k += 4) {
            float4 cv0 = ct4[(size_t)(k+0) * 256 + t];
            float4 cv1 = ct4[(size_t)(k+1) * 256 + t];
            float4 cv2 = ct4[(size_t)(k+2) * 256 + t];
            float4 cv3 = ct4[(size_t)(k+3) * 256 + t];
            #pragma unroll
            for (int r = 0; r < BR; ++r) {
                float4 xv = *(const float4*)&xr[r * D + k];
                acc[r][0] = fmaf(xv.x, cv0.x, acc[r][0]);
                acc[r][1] = fmaf(xv.x, cv0.y, acc[r][1]);
                acc[r][2] = fmaf(xv.x, cv0.z, acc[r][2]);
                acc[r][3] = fmaf(xv.x, cv0.w, acc[r][3]);
                acc[r][0] = fmaf(xv.y, cv1.x, acc[r][0]);
                acc[r][1] = fmaf(xv.y, cv1.y, acc[r][1]);
                acc[r][2] = fmaf(xv.y, cv1.z, acc[r][2]);
                acc[r][3] = fmaf(xv.y, cv1.w, acc[r][3]);
                acc[r][0] = fmaf(xv.z, cv2.x, acc[r][0]);
                acc[r][1] = fmaf(xv.z, cv2.y, acc[r][1]);
                acc[r][2] = fmaf(xv.z, cv2.z, acc[r][2]);
                acc[r][3] = fmaf(xv.z, cv2.w, acc[r][3]);
                acc[r][0] = fmaf(xv.w, cv3.x, acc[r][0]);
                acc[r][1] = fmaf(xv.w, cv3.y, acc[r][1]);
                acc[r][2] = fmaf(xv.w, cv3.z, acc[r][2]);
                acc[r][3] = fmaf(xv.w, cv3.w, acc[r][3]);
            }
        }

        float cn0 = cnorm[4*t+0], cn1 = cnorm[4*t+1], cn2 = cnorm[4*t+2], cn3 = cnorm[4*t+3];
        for (int r = 0; r < BR; ++r) {
            float s0 = fmaf(-2.f, acc[r][0], cn0);
            float s1 = fmaf(-2.f, acc[r][1], cn1);
            float s2 = fmaf(-2.f, acc[r][2], cn2);
            float s3 = fmaf(-2.f, acc[r][3], cn3);
            float lm1 = s0; int li = 4*t;
            float lm2 = FLT_MAX;
            if (s1 < lm1) { lm2 = lm1; lm1 = s1; li = 4*t+1; } else lm2 = s1;
            if (s2 < lm1) { lm2 = lm1; lm1 = s2; li = 4*t+2; } else lm2 = fminf(lm2, s2);
            if (s3 < lm1) { lm2 = lm1; lm1 = s3; li = 4*t+3; } else lm2 = fminf(lm2, s3);
            // wave-wide butterfly merge (64 lanes all hold candidates of row r)
            #pragma unroll
            for (int off = 1; off < 64; off <<= 1) {
                float o1 = __shfl_xor(lm1, off, 64);
                float o2 = __shfl_xor(lm2, off, 64);
                int   oi = __shfl_xor(li,  off, 64);
                if (o1 < lm1 || (o1 == lm1 && oi < li)) { lm2 = fminf(lm1, o2); lm1 = o1; li = oi; }
                else lm2 = fminf(lm2, o1);
            }
            // cross-wave (4 waves) via LDS: wave w writes slot, then merge by t==0
            const int w = t >> 6;
            if ((t & 63) == 0) { wm1[w] = lm1; wm2[w] = lm2; wi_[w] = li; }
            __syncthreads();
            if (t == 0) {
                float b1 = wm1[0], b2 = wm2[0]; int bi = wi_[0];
                #pragma unroll
                for (int ww = 1; ww < 4; ++ww) {
                    float o1 = wm1[ww], o2 = wm2[ww]; int oi = wi_[ww];
                    if (o1 < b1 || (o1 == b1 && oi < bi)) { b2 = fminf(b1, o2); b1 = o1; bi = oi; }
                    else b2 = fminf(b2, o1);
                }
                const int rg = rows_s[r];
                out_i[rg] = (float)bi;
                winc_s[r] = bi;
                if (b2 - b1 < EPS2) {
                    int s = atomicAdd(count2, 1);
                    rowlist2[s] = rg;
                }
            }
            __syncthreads();
        }
        // gather quantized rows
        #pragma unroll
        for (int p = 0; p < BR * 64 / 256; ++p) {
            int flat = p * 256 + t;
            int r = flat >> 6, q = flat & 63;
            float4 v = ((const float4*)codes)[(size_t)winc_s[r] * 64 + q];
            ((float4*)out_q)[(size_t)rows_s[r] * 64 + q] = v;
        }
        __syncthreads();
    }
}

// ---- tier-2: exact fp64 rescore; smallest index within DELTA (proven round 5) ----
__global__ __launch_bounds__(256)
void rescue_exact(const float* __restrict__ x, const float* __restrict__ codes,
                  const int* __restrict__ count, const int* __restrict__ rowlist,
                  float* __restrict__ out_q, float* __restrict__ out_i) {
    __shared__ float  xrow[D];
    __shared__ double dbuf[C];
    __shared__ double rmin[256];
    __shared__ int    ridx[256];
    const int t = threadIdx.x;
    const int n = *count;
    for (int idx = blockIdx.x; idx < n; idx += gridDim.x) {
        const int row = rowlist[idx];
        __syncthreads();
        xrow[t] = x[(size_t)row * D + t];
        __syncthreads();
        double lmin = 1e300;
        #pragma unroll
        for (int j = 0; j < 4; ++j) {
            const int c = 4 * t + j;
            const float* cp = codes + (size_t)c * D;
            double s = 0.0;
            for (int k = 0; k < D; k += 4) {
                float4 cv = *(const float4*)(cp + k);
                double d0 = (double)xrow[k+0] - (double)cv.x;
                double d1 = (double)xrow[k+1] - (double)cv.y;
                double d2 = (double)xrow[k+2] - (double)cv.z;
                double d3 = (double)xrow[k+3] - (double)cv.w;
                s += d0*d0 + d1*d1 + d2*d2 + d3*d3;
            }
            dbuf[c] = s;
            lmin = fmin(lmin, s);
        }
        rmin[t] = lmin;
        __syncthreads();
        for (int sft = 128; sft > 0; sft >>= 1) {
            if (t < sft) rmin[t] = fmin(rmin[t], rmin[t + sft]);
            __syncthreads();
        }
        const double dstar = rmin[0];
        int lidx = INT_MAX;
        #pragma unroll
        for (int j = 0; j < 4; ++j) {
            const int c = 4 * t + j;
            if (dbuf[c] < dstar + DELTA && c < lidx) lidx = c;
        }
        ridx[t] = lidx;
        __syncthreads();
        for (int sft = 128; sft > 0; sft >>= 1) {
            if (t < sft) ridx[t] = min(ridx[t], ridx[t + sft]);
            __syncthreads();
        }
        const int winc = ridx[0];
        if (t == 0) out_i[row] = (float)winc;
        if (t < 64) {
            float4 cv = ((const float4*)(codes + (size_t)winc * D))[t];
            ((float4*)(out_q + (size_t)row * D))[t] = cv;
        }
        __syncthreads();
    }
}

extern "C" void kernel_launch(void* const* d_in, const int* in_sizes, int n_in,
                              void* d_out, int out_size, void* d_ws, size_t ws_size,
                              hipStream_t stream) {
    const float* x     = (const float*)d_in[0];
    const float* codes = (const float*)d_in[1];
    const int N = in_sizes[0] / D;                 // 65536

    char* ws = (char*)d_ws;
    float*    cnorm   = (float*)ws;                       ws += C * 4;              // 4 KB
    float*    codes_t = (float*)ws;                       ws += (size_t)D * C * 4;  // 1 MB
    _Float16* codes_h = (_Float16*)ws;                    ws += (size_t)C * D * 2;  // 512 KB
    int*      count1  = (int*)ws;                         ws += 16;
    int*      count2  = (int*)ws;                         ws += 16;
    int*      rowlist1 = (int*)ws;                        ws += (size_t)N * 4;
    int*      rowlist2 = (int*)ws;

    float* out_q = (float*)d_out;
    float* out_i = out_q + (size_t)N * D;

    prep<<<C / 4, 256, 0, stream>>>(codes, cnorm, codes_h, codes_t, count1, count2);
    codebook_mfma<<<N / 64, 256, 0, stream>>>(x, codes_h, codes, cnorm,
                                              out_q, out_i, count1, rowlist1);
    rescue32<<<256, 256, 0, stream>>>(x, codes, codes_t, cnorm, count1, rowlist1,
                                      out_q, out_i, count2, rowlist2);
    rescue_exact<<<128, 256, 0, stream>>>(x, codes, count2, rowlist2, out_q, out_i);
}

// Round 2
// 415.003 us; speedup vs baseline: 1.1342x; 1.1342x over previous
//
#include <hip/hip_runtime.h>
#include <float.h>
#include <limits.h>

// Codebook / VQ: x [65536][256] fp32, codes [1024][256] fp32
// out: quantized [65536][256] fp32, then indices [65536] as fp32 values.
// Tiered: fp16 MFMA GEMM argmin (all rows) -> fp32 rescue (gap<EPS1 rows)
//        -> fp64+DELTA smallest-index rescue (gap<EPS2 rows, proven round 5).
// Round 2: fit the 4-waves/SIMD register budget for real. 4x2 MFMA tile per
// chunk (32 acc regs, 8 chunks of 32 codes) so acc+K1/K2+frags ~105 regs
// <= 128 cap -> no spill (round-1 spilled: VGPR=64, WRITE_SIZE +239MB).
// B operand re-packed tile-major in prep: each bf load = one coalesced 1KB
// segment, wave-uniform base + kc*512 immediate offset.
#define D     256
#define C     1024
#define EPS1  0.45f     // fp16-MFMA gap flag: 0.3 (fp16 err) + 0.125 (key truncation) + slack
#define EPS2  0.02f     // fp32 gap flag (proven)
#define DELTA 1.0e-4    // np ulp-collision window on exact fp64 distances
#define BR    16        // rows per batch in fp32 rescue

typedef _Float16 half8 __attribute__((ext_vector_type(8)));
typedef _Float16 half4_t __attribute__((ext_vector_type(4)));
typedef float v4f __attribute__((ext_vector_type(4)));

static __device__ __forceinline__ unsigned umin_(unsigned a, unsigned b) { return a < b ? a : b; }
static __device__ __forceinline__ unsigned umax_(unsigned a, unsigned b) { return a > b ? a : b; }

// prep: cnorm fp32, codes -> fp16 TILED copy, codes -> fp32 transpose, zero counters
// Tiled fp16 layout: tile t = c>>4 (16 codes), fragment kc = k>>5, lane
// l = quad*16 + (c&15) with quad = (k>>3)&3, elem = k&7:
//   codes_h[t*4096 + kc*512 + l*8 + elem]
// so a wave's B-fragment load for (tile, kc) is codes_h + t*4096 + kc*512 + lane*8
// == one contiguous 1KB segment.
__global__ __launch_bounds__(256)
void prep(const float* __restrict__ codes, float* __restrict__ cnorm,
          _Float16* __restrict__ codes_h, float* __restrict__ codes_t,
          int* __restrict__ count1, int* __restrict__ count2) {
    if (blockIdx.x == 0 && threadIdx.x == 0) { *count1 = 0; *count2 = 0; }
    int c    = (blockIdx.x * blockDim.x + threadIdx.x) >> 6;   // 0..1023, one code per wave
    int lane = threadIdx.x & 63;
    float4 v = ((const float4*)(codes + (size_t)c * D))[lane]; // k = 4*lane..4*lane+3
    // fp16 tiled write (4 halfs stay inside one 8-elem group: (4*lane)&7 in {0,4})
    half4_t h; h[0] = (_Float16)v.x; h[1] = (_Float16)v.y; h[2] = (_Float16)v.z; h[3] = (_Float16)v.w;
    {
        int kc   = lane >> 3;            // (4*lane)>>5
        int quad = (lane >> 1) & 3;      // ((4*lane)>>3)&3
        int e    = (lane & 1) * 4;       // (4*lane)&7
        size_t off = (size_t)(c >> 4) * 4096 + kc * 512 + (quad * 16 + (c & 15)) * 8 + e;
        *(half4_t*)(codes_h + off) = h;
    }
    // fp32 transpose codes_t[k][c]
    codes_t[(size_t)(4*lane+0) * C + c] = v.x;
    codes_t[(size_t)(4*lane+1) * C + c] = v.y;
    codes_t[(size_t)(4*lane+2) * C + c] = v.z;
    codes_t[(size_t)(4*lane+3) * C + c] = v.w;
    float s = v.x * v.x + v.y * v.y + v.z * v.z + v.w * v.w;
    #pragma unroll
    for (int off = 32; off >= 1; off >>= 1) s += __shfl_xor(s, off, 64);
    if (lane == 0) cnorm[c] = s;
}

// ---- main: fp16 MFMA distance argmin, 64 rows/block, code-split across 4 waves ----
// Packed key: scores shifted +1024 (positive => IEEE bits order as uints), low
// 10 mantissa bits replaced by code index => u32 min is lexicographic
// (trunc score, index). Truncation error < 0.125 absorbed into EPS1.
#define LDA 264   // fp16 leading dim of x-tile (pad 8 halves)
__global__ __launch_bounds__(256, 4)
void codebook_mfma(const float* __restrict__ x, const _Float16* __restrict__ codes_h,
                   const float* __restrict__ codes, const float* __restrict__ cnorm,
                   float* __restrict__ out_q, float* __restrict__ out_i,
                   int* __restrict__ count1, int* __restrict__ rowlist1) {
    __shared__ __align__(16) _Float16 Ah[64 * LDA];   // 33792 B
    __shared__ uint2 red[64][4];                      // 2048 B: per-(row,wave) top-2 keys
    __shared__ int win[64];

    const int tid  = threadIdx.x;
    const int w    = tid >> 6, lane = tid & 63;
    const int quad = lane >> 4, l15 = lane & 15;
    const int row0 = blockIdx.x * 64;

    // stage x-tile fp32 -> fp16 LDS [64][LDA]
    #pragma unroll
    for (int p = 0; p < 16; ++p) {
        int flat = p * 256 + tid;          // 0..4095
        int r = flat >> 6, q = flat & 63;  // row, float4-idx
        float4 v = ((const float4*)x)[(size_t)(row0 + r) * 64 + q];
        half4_t h; h[0]=(_Float16)v.x; h[1]=(_Float16)v.y; h[2]=(_Float16)v.z; h[3]=(_Float16)v.w;
        *(half4_t*)(Ah + r * LDA + 4 * q) = h;
    }
    __syncthreads();

    // per-lane top-2 packed keys over 16 rows; row = ra*16 + quad*4 + reg
    unsigned K1[16], K2[16];
    #pragma unroll
    for (int i = 0; i < 16; ++i) { K1[i] = 0xFFFFFFFFu; K2[i] = 0xFFFFFFFFu; }

    // wave w covers codes [w*256, w*256+256) in 8 chunks of 32 (2 tiles of 16)
    for (int ct = 0; ct < 8; ++ct) {
        v4f acc[4][2];
        #pragma unroll
        for (int ra = 0; ra < 4; ++ra) {
            acc[ra][0] = (v4f){0.f, 0.f, 0.f, 0.f};
            acc[ra][1] = (v4f){0.f, 0.f, 0.f, 0.f};
        }

        const int c0 = w * 256 + ct * 32;
        const _Float16* bt = codes_h + (size_t)(c0 >> 4) * 4096 + lane * 8;
        #pragma unroll
        for (int kc = 0; kc < 8; ++kc) {
            half8 bf0 = *(const half8*)(bt + kc * 512);
            half8 bf1 = *(const half8*)(bt + 4096 + kc * 512);
            half8 af[4];
            #pragma unroll
            for (int ra = 0; ra < 4; ++ra)
                af[ra] = *(const half8*)(Ah + (ra*16 + l15) * LDA + kc*32 + quad*8);
            #pragma unroll
            for (int ra = 0; ra < 4; ++ra) {
                acc[ra][0] = __builtin_amdgcn_mfma_f32_16x16x32_f16(af[ra], bf0, acc[ra][0], 0, 0, 0);
                acc[ra][1] = __builtin_amdgcn_mfma_f32_16x16x32_f16(af[ra], bf1, acc[ra][1], 0, 0, 0);
            }
        }

        // score = (cnorm + 1024) - 2*dot  (positive); pack + top-2 merge
        const int   col0 = c0 + l15, col1 = c0 + 16 + l15;
        const float cn0  = cnorm[col0] + 1024.0f;
        const float cn1  = cnorm[col1] + 1024.0f;
        #pragma unroll
        for (int ra = 0; ra < 4; ++ra)
            #pragma unroll
            for (int reg = 0; reg < 4; ++reg) {
                const int m = ra * 4 + reg;
                unsigned k0 = (__float_as_uint(fmaf(-2.0f, acc[ra][0][reg], cn0)) & 0xFFFFFC00u) | (unsigned)col0;
                unsigned k1 = (__float_as_uint(fmaf(-2.0f, acc[ra][1][reg], cn1)) & 0xFFFFFC00u) | (unsigned)col1;
                unsigned lo = umin_(k0, k1), hi = umax_(k0, k1);
                unsigned t  = umax_(K1[m], lo);
                K2[m] = umin_(umin_(K2[m], hi), t);
                K1[m] = umin_(K1[m], lo);
            }
    }

    // wave-internal merge across the 16 lanes (same quad group) holding the
    // row's candidates: butterfly over l15 (masks < 16 stay in-group)
    #pragma unroll
    for (int m = 0; m < 16; ++m) {
        #pragma unroll
        for (int off = 1; off < 16; off <<= 1) {
            unsigned o1 = (unsigned)__shfl_xor((int)K1[m], off, 64);
            unsigned o2 = (unsigned)__shfl_xor((int)K2[m], off, 64);
            unsigned t  = umax_(K1[m], o1);
            K2[m] = umin_(umin_(K2[m], o2), t);
            K1[m] = umin_(K1[m], o1);
        }
    }
    if (l15 == 0) {
        #pragma unroll
        for (int m = 0; m < 16; ++m) {
            int row = (m >> 2) * 16 + quad * 4 + (m & 3);
            red[row][w] = make_uint2(K1[m], K2[m]);
        }
    }
    __syncthreads();

    // cross-wave merge (4 waves), final winner + gap flag
    if (tid < 64) {
        unsigned b1 = red[tid][0].x, b2 = red[tid][0].y;
        #pragma unroll
        for (int ww = 1; ww < 4; ++ww) {
            unsigned o1 = red[tid][ww].x, o2 = red[tid][ww].y;
            unsigned t  = umax_(b1, o1);
            b2 = umin_(umin_(b2, o2), t);
            b1 = umin_(b1, o1);
        }
        int bi = (int)(b1 & 0x3FFu);
        win[tid] = bi;
        out_i[row0 + tid] = (float)bi;
        float g1 = __uint_as_float(b1 & 0xFFFFFC00u);
        float g2 = __uint_as_float(b2 & 0xFFFFFC00u);
        if (g2 - g1 < EPS1) {
            int s = atomicAdd(count1, 1);
            rowlist1[s] = row0 + tid;
        }
    }
    __syncthreads();

    // gather quantized rows (flagged rows overwritten by rescues later)
    #pragma unroll
    for (int p = 0; p < 16; ++p) {
        int flat = p * 256 + tid;
        int r = flat >> 6, q = flat & 63;
        float4 v = ((const float4*)codes)[(size_t)win[r] * 64 + q];
        ((float4*)out_q)[(size_t)(row0 + r) * 64 + q] = v;
    }
}

// ---- tier-1: fp32 rescore of flagged rows, BR rows/block share codes stream ----
__global__ __launch_bounds__(256)
void rescue32(const float* __restrict__ x, const float* __restrict__ codes,
              const float* __restrict__ codes_t, const float* __restrict__ cnorm,
              const int* __restrict__ count1, const int* __restrict__ rowlist1,
              float* __restrict__ out_q, float* __restrict__ out_i,
              int* __restrict__ count2, int* __restrict__ rowlist2) {
    __shared__ __align__(16) float xr[BR * D];   // 16 KB
    __shared__ int rows_s[BR];
    __shared__ int winc_s[BR];
    __shared__ float wm1[4], wm2[4];
    __shared__ int wi_[4];
    const int t = threadIdx.x;
    const int n1 = *count1;
    if (n1 == 0) return;
    const int nb = (n1 + BR - 1) / BR;
    const float4* ct4 = (const float4*)codes_t;  // [k][c/4]

    for (int b = blockIdx.x; b < nb; b += gridDim.x) {
        __syncthreads();
        if (t < BR) {
            int idx = b * BR + t;
            if (idx >= n1) idx = n1 - 1;           // duplicate tail rows (benign)
            rows_s[t] = rowlist1[idx];
        }
        __syncthreads();
        #pragma unroll
        for (int p = 0; p < BR * 64 / 256; ++p) {  // 4 iters
            int flat = p * 256 + t;
            int r = flat >> 6, q = flat & 63;
            ((float4*)xr)[r * 64 + q] = ((const float4*)x)[(size_t)rows_s[r] * 64 + q];
        }
        __syncthreads();

        float acc[BR][4];
        #pragma unroll
        for (int r = 0; r < BR; ++r)
            #pragma unroll
            for (int j = 0; j < 4; ++j) acc[r][j] = 0.f;

        for (int k = 0; k < D; k += 4) {
            float4 cv0 = ct4[(size_t)(k+0) * 256 + t];
            float4 cv1 = ct4[(size_t)(k+1) * 256 + t];
            float4 cv2 = ct4[(size_t)(k+2) * 256 + t];
            float4 cv3 = ct4[(size_t)(k+3) * 256 + t];
            #pragma unroll
            for (int r = 0; r < BR; ++r) {
                float4 xv = *(const float4*)&xr[r * D + k];
                acc[r][0] = fmaf(xv.x, cv0.x, acc[r][0]);
                acc[r][1] = fmaf(xv.x, cv0.y, acc[r][1]);
                acc[r][2] = fmaf(xv.x, cv0.z, acc[r][2]);
                acc[r][3] = fmaf(xv.x, cv0.w, acc[r][3]);
                acc[r][0] = fmaf(xv.y, cv1.x, acc[r][0]);
                acc[r][1] = fmaf(xv.y, cv1.y, acc[r][1]);
                acc[r][2] = fmaf(xv.y, cv1.z, acc[r][2]);
                acc[r][3] = fmaf(xv.y, cv1.w, acc[r][3]);
                acc[r][0] = fmaf(xv.z, cv2.x, acc[r][0]);
                acc[r][1] = fmaf(xv.z, cv2.y, acc[r][1]);
                acc[r][2] = fmaf(xv.z, cv2.z, acc[r][2]);
                acc[r][3] = fmaf(xv.z, cv2.w, acc[r][3]);
                acc[r][0] = fmaf(xv.w, cv3.x, acc[r][0]);
                acc[r][1] = fmaf(xv.w, cv3.y, acc[r][1]);
                acc[r][2] = fmaf(xv.w, cv3.z, acc[r][2]);
                acc[r][3] = fmaf(xv.w, cv3.w, acc[r][3]);
            }
        }

        float cn0 = cnorm[4*t+0], cn1 = cnorm[4*t+1], cn2 = cnorm[4*t+2], cn3 = cnorm[4*t+3];
        for (int r = 0; r < BR; ++r) {
            float s0 = fmaf(-2.f, acc[r][0], cn0);
            float s1 = fmaf(-2.f, acc[r][1], cn1);
            float s2 = fmaf(-2.f, acc[r][2], cn2);
            float s3 = fmaf(-2.f, acc[r][3], cn3);
            float lm1 = s0; int li = 4*t;
            float lm2 = FLT_MAX;
            if (s1 < lm1) { lm2 = lm1; lm1 = s1; li = 4*t+1; } else lm2 = s1;
            if (s2 < lm1) { lm2 = lm1; lm1 = s2; li = 4*t+2; } else lm2 = fminf(lm2, s2);
            if (s3 < lm1) { lm2 = lm1; lm1 = s3; li = 4*t+3; } else lm2 = fminf(lm2, s3);
            // wave-wide butterfly merge (64 lanes all hold candidates of row r)
            #pragma unroll
            for (int off = 1; off < 64; off <<= 1) {
                float o1 = __shfl_xor(lm1, off, 64);
                float o2 = __shfl_xor(lm2, off, 64);
                int   oi = __shfl_xor(li,  off, 64);
                if (o1 < lm1 || (o1 == lm1 && oi < li)) { lm2 = fminf(lm1, o2); lm1 = o1; li = oi; }
                else lm2 = fminf(lm2, o1);
            }
            // cross-wave (4 waves) via LDS: wave w writes slot, then merge by t==0
            const int w = t >> 6;
            if ((t & 63) == 0) { wm1[w] = lm1; wm2[w] = lm2; wi_[w] = li; }
            __syncthreads();
            if (t == 0) {
                float b1 = wm1[0], b2 = wm2[0]; int bi = wi_[0];
                #pragma unroll
                for (int ww = 1; ww < 4; ++ww) {
                    float o1 = wm1[ww], o2 = wm2[ww]; int oi = wi_[ww];
                    if (o1 < b1 || (o1 == b1 && oi < bi)) { b2 = fminf(b1, o2); b1 = o1; bi = oi; }
                    else b2 = fminf(b2, o1);
                }
                const int rg = rows_s[r];
                out_i[rg] = (float)bi;
                winc_s[r] = bi;
                if (b2 - b1 < EPS2) {
                    int s = atomicAdd(count2, 1);
                    rowlist2[s] = rg;
                }
            }
            __syncthreads();
        }
        // gather quantized rows
        #pragma unroll
        for (int p = 0; p < BR * 64 / 256; ++p) {
            int flat = p * 256 + t;
            int r = flat >> 6, q = flat & 63;
            float4 v = ((const float4*)codes)[(size_t)winc_s[r] * 64 + q];
            ((float4*)out_q)[(size_t)rows_s[r] * 64 + q] = v;
        }
        __syncthreads();
    }
}

// ---- tier-2: exact fp64 rescore; smallest index within DELTA (proven round 5) ----
__global__ __launch_bounds__(256)
void rescue_exact(const float* __restrict__ x, const float* __restrict__ codes,
                  const int* __restrict__ count, const int* __restrict__ rowlist,
                  float* __restrict__ out_q, float* __restrict__ out_i) {
    __shared__ float  xrow[D];
    __shared__ double dbuf[C];
    __shared__ double rmin[256];
    __shared__ int    ridx[256];
    const int t = threadIdx.x;
    const int n = *count;
    for (int idx = blockIdx.x; idx < n; idx += gridDim.x) {
        const int row = rowlist[idx];
        __syncthreads();
        xrow[t] = x[(size_t)row * D + t];
        __syncthreads();
        double lmin = 1e300;
        #pragma unroll
        for (int j = 0; j < 4; ++j) {
            const int c = 4 * t + j;
            const float* cp = codes + (size_t)c * D;
            double s = 0.0;
            for (int k = 0; k < D; k += 4) {
                float4 cv = *(const float4*)(cp + k);
                double d0 = (double)xrow[k+0] - (double)cv.x;
                double d1 = (double)xrow[k+1] - (double)cv.y;
                double d2 = (double)xrow[k+2] - (double)cv.z;
                double d3 = (double)xrow[k+3] - (double)cv.w;
                s += d0*d0 + d1*d1 + d2*d2 + d3*d3;
            }
            dbuf[c] = s;
            lmin = fmin(lmin, s);
        }
        rmin[t] = lmin;
        __syncthreads();
        for (int sft = 128; sft > 0; sft >>= 1) {
            if (t < sft) rmin[t] = fmin(rmin[t], rmin[t + sft]);
            __syncthreads();
        }
        const double dstar = rmin[0];
        int lidx = INT_MAX;
        #pragma unroll
        for (int j = 0; j < 4; ++j) {
            const int c = 4 * t + j;
            if (dbuf[c] < dstar + DELTA && c < lidx) lidx = c;
        }
        ridx[t] = lidx;
        __syncthreads();
        for (int sft = 128; sft > 0; sft >>= 1) {
            if (t < sft) ridx[t] = min(ridx[t], ridx[t + sft]);
            __syncthreads();
        }
        const int winc = ridx[0];
        if (t == 0) out_i[row] = (float)winc;
        if (t < 64) {
            float4 cv = ((const float4*)(codes + (size_t)winc * D))[t];
            ((float4*)(out_q + (size_t)row * D))[t] = cv;
        }
        __syncthreads();
    }
}

extern "C" void kernel_launch(void* const* d_in, const int* in_sizes, int n_in,
                              void* d_out, int out_size, void* d_ws, size_t ws_size,
                              hipStream_t stream) {
    const float* x     = (const float*)d_in[0];
    const float* codes = (const float*)d_in[1];
    const int N = in_sizes[0] / D;                 // 65536

    char* ws = (char*)d_ws;
    float*    cnorm   = (float*)ws;                       ws += C * 4;              // 4 KB
    float*    codes_t = (float*)ws;                       ws += (size_t)D * C * 4;  // 1 MB
    _Float16* codes_h = (_Float16*)ws;                    ws += (size_t)C * D * 2;  // 512 KB (tiled)
    int*      count1  = (int*)ws;                         ws += 16;
    int*      count2  = (int*)ws;                         ws += 16;
    int*      rowlist1 = (int*)ws;                        ws += (size_t)N * 4;
    int*      rowlist2 = (int*)ws;

    float* out_q = (float*)d_out;
    float* out_i = out_q + (size_t)N * D;

    prep<<<C / 4, 256, 0, stream>>>(codes, cnorm, codes_h, codes_t, count1, count2);
    codebook_mfma<<<N / 64, 256, 0, stream>>>(x, codes_h, codes, cnorm,
                                              out_q, out_i, count1, rowlist1);
    rescue32<<<256, 256, 0, stream>>>(x, codes, codes_t, cnorm, count1, rowlist1,
                                      out_q, out_i, count2, rowlist2);
    rescue_exact<<<128, 256, 0, stream>>>(x, codes, count2, rowlist2, out_q, out_i);
}

// Round 3
// 409.304 us; speedup vs baseline: 1.1500x; 1.0139x over previous
//
#include <hip/hip_runtime.h>
#include <float.h>
#include <limits.h>

// Codebook / VQ: x [65536][256] fp32, codes [1024][256] fp32
// out: quantized [65536][256] fp32, then indices [65536] as fp32 values.
// Tiered: fp16 MFMA GEMM argmin (all rows) -> fp32 rescue (gap<EPS1 rows)
//        -> fp64+DELTA smallest-index rescue (gap<EPS2 rows, proven round 5).
// Round 3: __launch_bounds__(256,3). Round-2's (256,4) made the compiler
// split the 128-reg budget 64 arch / 64 accum -> K1/K2+frags spilled
// (FETCH_SIZE 469MB of scratch re-reads, 42% HBM on spill traffic).
// Round-2 PMC proved occupancy 40% is achievable; (256,3) keeps ~37%
// occupancy with a 170-reg budget so nothing spills.
#define D     256
#define C     1024
#define EPS1  0.45f     // fp16-MFMA gap flag: 0.3 (fp16 err) + 0.125 (key truncation) + slack
#define EPS2  0.02f     // fp32 gap flag (proven)
#define DELTA 1.0e-4    // np ulp-collision window on exact fp64 distances
#define BR    16        // rows per batch in fp32 rescue

typedef _Float16 half8 __attribute__((ext_vector_type(8)));
typedef _Float16 half4_t __attribute__((ext_vector_type(4)));
typedef float v4f __attribute__((ext_vector_type(4)));

static __device__ __forceinline__ unsigned umin_(unsigned a, unsigned b) { return a < b ? a : b; }
static __device__ __forceinline__ unsigned umax_(unsigned a, unsigned b) { return a > b ? a : b; }

// prep: cnorm fp32, codes -> fp16 TILED copy, codes -> fp32 transpose, zero counters
// Tiled fp16 layout: tile t = c>>4 (16 codes), fragment kc = k>>5, lane
// l = quad*16 + (c&15) with quad = (k>>3)&3, elem = k&7:
//   codes_h[t*4096 + kc*512 + l*8 + elem]
// so a wave's B-fragment load for (tile, kc) is codes_h + t*4096 + kc*512 + lane*8
// == one contiguous 1KB segment.
__global__ __launch_bounds__(256)
void prep(const float* __restrict__ codes, float* __restrict__ cnorm,
          _Float16* __restrict__ codes_h, float* __restrict__ codes_t,
          int* __restrict__ count1, int* __restrict__ count2) {
    if (blockIdx.x == 0 && threadIdx.x == 0) { *count1 = 0; *count2 = 0; }
    int c    = (blockIdx.x * blockDim.x + threadIdx.x) >> 6;   // 0..1023, one code per wave
    int lane = threadIdx.x & 63;
    float4 v = ((const float4*)(codes + (size_t)c * D))[lane]; // k = 4*lane..4*lane+3
    // fp16 tiled write (4 halfs stay inside one 8-elem group: (4*lane)&7 in {0,4})
    half4_t h; h[0] = (_Float16)v.x; h[1] = (_Float16)v.y; h[2] = (_Float16)v.z; h[3] = (_Float16)v.w;
    {
        int kc   = lane >> 3;            // (4*lane)>>5
        int quad = (lane >> 1) & 3;      // ((4*lane)>>3)&3
        int e    = (lane & 1) * 4;       // (4*lane)&7
        size_t off = (size_t)(c >> 4) * 4096 + kc * 512 + (quad * 16 + (c & 15)) * 8 + e;
        *(half4_t*)(codes_h + off) = h;
    }
    // fp32 transpose codes_t[k][c]
    codes_t[(size_t)(4*lane+0) * C + c] = v.x;
    codes_t[(size_t)(4*lane+1) * C + c] = v.y;
    codes_t[(size_t)(4*lane+2) * C + c] = v.z;
    codes_t[(size_t)(4*lane+3) * C + c] = v.w;
    float s = v.x * v.x + v.y * v.y + v.z * v.z + v.w * v.w;
    #pragma unroll
    for (int off = 32; off >= 1; off >>= 1) s += __shfl_xor(s, off, 64);
    if (lane == 0) cnorm[c] = s;
}

// ---- main: fp16 MFMA distance argmin, 64 rows/block, code-split across 4 waves ----
// Packed key: scores shifted +1024 (positive => IEEE bits order as uints), low
// 10 mantissa bits replaced by code index => u32 min is lexicographic
// (trunc score, index). Truncation error < 0.125 absorbed into EPS1.
#define LDA 264   // fp16 leading dim of x-tile (pad 8 halves)
__global__ __launch_bounds__(256, 3)
void codebook_mfma(const float* __restrict__ x, const _Float16* __restrict__ codes_h,
                   const float* __restrict__ codes, const float* __restrict__ cnorm,
                   float* __restrict__ out_q, float* __restrict__ out_i,
                   int* __restrict__ count1, int* __restrict__ rowlist1) {
    __shared__ __align__(16) _Float16 Ah[64 * LDA];   // 33792 B
    __shared__ uint2 red[64][4];                      // 2048 B: per-(row,wave) top-2 keys
    __shared__ int win[64];

    const int tid  = threadIdx.x;
    const int w    = tid >> 6, lane = tid & 63;
    const int quad = lane >> 4, l15 = lane & 15;
    const int row0 = blockIdx.x * 64;

    // stage x-tile fp32 -> fp16 LDS [64][LDA]
    #pragma unroll
    for (int p = 0; p < 16; ++p) {
        int flat = p * 256 + tid;          // 0..4095
        int r = flat >> 6, q = flat & 63;  // row, float4-idx
        float4 v = ((const float4*)x)[(size_t)(row0 + r) * 64 + q];
        half4_t h; h[0]=(_Float16)v.x; h[1]=(_Float16)v.y; h[2]=(_Float16)v.z; h[3]=(_Float16)v.w;
        *(half4_t*)(Ah + r * LDA + 4 * q) = h;
    }
    __syncthreads();

    // per-lane top-2 packed keys over 16 rows; row = ra*16 + quad*4 + reg
    unsigned K1[16], K2[16];
    #pragma unroll
    for (int i = 0; i < 16; ++i) { K1[i] = 0xFFFFFFFFu; K2[i] = 0xFFFFFFFFu; }

    // wave w covers codes [w*256, w*256+256) in 8 chunks of 32 (2 tiles of 16)
    for (int ct = 0; ct < 8; ++ct) {
        v4f acc[4][2];
        #pragma unroll
        for (int ra = 0; ra < 4; ++ra) {
            acc[ra][0] = (v4f){0.f, 0.f, 0.f, 0.f};
            acc[ra][1] = (v4f){0.f, 0.f, 0.f, 0.f};
        }

        const int c0 = w * 256 + ct * 32;
        const _Float16* bt = codes_h + (size_t)(c0 >> 4) * 4096 + lane * 8;
        #pragma unroll
        for (int kc = 0; kc < 8; ++kc) {
            half8 bf0 = *(const half8*)(bt + kc * 512);
            half8 bf1 = *(const half8*)(bt + 4096 + kc * 512);
            half8 af[4];
            #pragma unroll
            for (int ra = 0; ra < 4; ++ra)
                af[ra] = *(const half8*)(Ah + (ra*16 + l15) * LDA + kc*32 + quad*8);
            #pragma unroll
            for (int ra = 0; ra < 4; ++ra) {
                acc[ra][0] = __builtin_amdgcn_mfma_f32_16x16x32_f16(af[ra], bf0, acc[ra][0], 0, 0, 0);
                acc[ra][1] = __builtin_amdgcn_mfma_f32_16x16x32_f16(af[ra], bf1, acc[ra][1], 0, 0, 0);
            }
        }

        // score = (cnorm + 1024) - 2*dot  (positive); pack + top-2 merge
        const int   col0 = c0 + l15, col1 = c0 + 16 + l15;
        const float cn0  = cnorm[col0] + 1024.0f;
        const float cn1  = cnorm[col1] + 1024.0f;
        #pragma unroll
        for (int ra = 0; ra < 4; ++ra)
            #pragma unroll
            for (int reg = 0; reg < 4; ++reg) {
                const int m = ra * 4 + reg;
                unsigned k0 = (__float_as_uint(fmaf(-2.0f, acc[ra][0][reg], cn0)) & 0xFFFFFC00u) | (unsigned)col0;
                unsigned k1 = (__float_as_uint(fmaf(-2.0f, acc[ra][1][reg], cn1)) & 0xFFFFFC00u) | (unsigned)col1;
                unsigned lo = umin_(k0, k1), hi = umax_(k0, k1);
                unsigned t  = umax_(K1[m], lo);
                K2[m] = umin_(umin_(K2[m], hi), t);
                K1[m] = umin_(K1[m], lo);
            }
    }

    // wave-internal merge across the 16 lanes (same quad group) holding the
    // row's candidates: butterfly over l15 (masks < 16 stay in-group)
    #pragma unroll
    for (int m = 0; m < 16; ++m) {
        #pragma unroll
        for (int off = 1; off < 16; off <<= 1) {
            unsigned o1 = (unsigned)__shfl_xor((int)K1[m], off, 64);
            unsigned o2 = (unsigned)__shfl_xor((int)K2[m], off, 64);
            unsigned t  = umax_(K1[m], o1);
            K2[m] = umin_(umin_(K2[m], o2), t);
            K1[m] = umin_(K1[m], o1);
        }
    }
    if (l15 == 0) {
        #pragma unroll
        for (int m = 0; m < 16; ++m) {
            int row = (m >> 2) * 16 + quad * 4 + (m & 3);
            red[row][w] = make_uint2(K1[m], K2[m]);
        }
    }
    __syncthreads();

    // cross-wave merge (4 waves), final winner + gap flag
    if (tid < 64) {
        unsigned b1 = red[tid][0].x, b2 = red[tid][0].y;
        #pragma unroll
        for (int ww = 1; ww < 4; ++ww) {
            unsigned o1 = red[tid][ww].x, o2 = red[tid][ww].y;
            unsigned t  = umax_(b1, o1);
            b2 = umin_(umin_(b2, o2), t);
            b1 = umin_(b1, o1);
        }
        int bi = (int)(b1 & 0x3FFu);
        win[tid] = bi;
        out_i[row0 + tid] = (float)bi;
        float g1 = __uint_as_float(b1 & 0xFFFFFC00u);
        float g2 = __uint_as_float(b2 & 0xFFFFFC00u);
        if (g2 - g1 < EPS1) {
            int s = atomicAdd(count1, 1);
            rowlist1[s] = row0 + tid;
        }
    }
    __syncthreads();

    // gather quantized rows (flagged rows overwritten by rescues later)
    #pragma unroll
    for (int p = 0; p < 16; ++p) {
        int flat = p * 256 + tid;
        int r = flat >> 6, q = flat & 63;
        float4 v = ((const float4*)codes)[(size_t)win[r] * 64 + q];
        ((float4*)out_q)[(size_t)(row0 + r) * 64 + q] = v;
    }
}

// ---- tier-1: fp32 rescore of flagged rows, BR rows/block share codes stream ----
__global__ __launch_bounds__(256)
void rescue32(const float* __restrict__ x, const float* __restrict__ codes,
              const float* __restrict__ codes_t, const float* __restrict__ cnorm,
              const int* __restrict__ count1, const int* __restrict__ rowlist1,
              float* __restrict__ out_q, float* __restrict__ out_i,
              int* __restrict__ count2, int* __restrict__ rowlist2) {
    __shared__ __align__(16) float xr[BR * D];   // 16 KB
    __shared__ int rows_s[BR];
    __shared__ int winc_s[BR];
    __shared__ float wm1[4], wm2[4];
    __shared__ int wi_[4];
    const int t = threadIdx.x;
    const int n1 = *count1;
    if (n1 == 0) return;
    const int nb = (n1 + BR - 1) / BR;
    const float4* ct4 = (const float4*)codes_t;  // [k][c/4]

    for (int b = blockIdx.x; b < nb; b += gridDim.x) {
        __syncthreads();
        if (t < BR) {
            int idx = b * BR + t;
            if (idx >= n1) idx = n1 - 1;           // duplicate tail rows (benign)
            rows_s[t] = rowlist1[idx];
        }
        __syncthreads();
        #pragma unroll
        for (int p = 0; p < BR * 64 / 256; ++p) {  // 4 iters
            int flat = p * 256 + t;
            int r = flat >> 6, q = flat & 63;
            ((float4*)xr)[r * 64 + q] = ((const float4*)x)[(size_t)rows_s[r] * 64 + q];
        }
        __syncthreads();

        float acc[BR][4];
        #pragma unroll
        for (int r = 0; r < BR; ++r)
            #pragma unroll
            for (int j = 0; j < 4; ++j) acc[r][j] = 0.f;

        for (int k = 0; k < D; k += 4) {
            float4 cv0 = ct4[(size_t)(k+0) * 256 + t];
            float4 cv1 = ct4[(size_t)(k+1) * 256 + t];
            float4 cv2 = ct4[(size_t)(k+2) * 256 + t];
            float4 cv3 = ct4[(size_t)(k+3) * 256 + t];
            #pragma unroll
            for (int r = 0; r < BR; ++r) {
                float4 xv = *(const float4*)&xr[r * D + k];
                acc[r][0] = fmaf(xv.x, cv0.x, acc[r][0]);
                acc[r][1] = fmaf(xv.x, cv0.y, acc[r][1]);
                acc[r][2] = fmaf(xv.x, cv0.z, acc[r][2]);
                acc[r][3] = fmaf(xv.x, cv0.w, acc[r][3]);
                acc[r][0] = fmaf(xv.y, cv1.x, acc[r][0]);
                acc[r][1] = fmaf(xv.y, cv1.y, acc[r][1]);
                acc[r][2] = fmaf(xv.y, cv1.z, acc[r][2]);
                acc[r][3] = fmaf(xv.y, cv1.w, acc[r][3]);
                acc[r][0] = fmaf(xv.z, cv2.x, acc[r][0]);
                acc[r][1] = fmaf(xv.z, cv2.y, acc[r][1]);
                acc[r][2] = fmaf(xv.z, cv2.z, acc[r][2]);
                acc[r][3] = fmaf(xv.z, cv2.w, acc[r][3]);
                acc[r][0] = fmaf(xv.w, cv3.x, acc[r][0]);
                acc[r][1] = fmaf(xv.w, cv3.y, acc[r][1]);
                acc[r][2] = fmaf(xv.w, cv3.z, acc[r][2]);
                acc[r][3] = fmaf(xv.w, cv3.w, acc[r][3]);
            }
        }

        float cn0 = cnorm[4*t+0], cn1 = cnorm[4*t+1], cn2 = cnorm[4*t+2], cn3 = cnorm[4*t+3];
        for (int r = 0; r < BR; ++r) {
            float s0 = fmaf(-2.f, acc[r][0], cn0);
            float s1 = fmaf(-2.f, acc[r][1], cn1);
            float s2 = fmaf(-2.f, acc[r][2], cn2);
            float s3 = fmaf(-2.f, acc[r][3], cn3);
            float lm1 = s0; int li = 4*t;
            float lm2 = FLT_MAX;
            if (s1 < lm1) { lm2 = lm1; lm1 = s1; li = 4*t+1; } else lm2 = s1;
            if (s2 < lm1) { lm2 = lm1; lm1 = s2; li = 4*t+2; } else lm2 = fminf(lm2, s2);
            if (s3 < lm1) { lm2 = lm1; lm1 = s3; li = 4*t+3; } else lm2 = fminf(lm2, s3);
            // wave-wide butterfly merge (64 lanes all hold candidates of row r)
            #pragma unroll
            for (int off = 1; off < 64; off <<= 1) {
                float o1 = __shfl_xor(lm1, off, 64);
                float o2 = __shfl_xor(lm2, off, 64);
                int   oi = __shfl_xor(li,  off, 64);
                if (o1 < lm1 || (o1 == lm1 && oi < li)) { lm2 = fminf(lm1, o2); lm1 = o1; li = oi; }
                else lm2 = fminf(lm2, o1);
            }
            // cross-wave (4 waves) via LDS: wave w writes slot, then merge by t==0
            const int w = t >> 6;
            if ((t & 63) == 0) { wm1[w] = lm1; wm2[w] = lm2; wi_[w] = li; }
            __syncthreads();
            if (t == 0) {
                float b1 = wm1[0], b2 = wm2[0]; int bi = wi_[0];
                #pragma unroll
                for (int ww = 1; ww < 4; ++ww) {
                    float o1 = wm1[ww], o2 = wm2[ww]; int oi = wi_[ww];
                    if (o1 < b1 || (o1 == b1 && oi < bi)) { b2 = fminf(b1, o2); b1 = o1; bi = oi; }
                    else b2 = fminf(b2, o1);
                }
                const int rg = rows_s[r];
                out_i[rg] = (float)bi;
                winc_s[r] = bi;
                if (b2 - b1 < EPS2) {
                    int s = atomicAdd(count2, 1);
                    rowlist2[s] = rg;
                }
            }
            __syncthreads();
        }
        // gather quantized rows
        #pragma unroll
        for (int p = 0; p < BR * 64 / 256; ++p) {
            int flat = p * 256 + t;
            int r = flat >> 6, q = flat & 63;
            float4 v = ((const float4*)codes)[(size_t)winc_s[r] * 64 + q];
            ((float4*)out_q)[(size_t)rows_s[r] * 64 + q] = v;
        }
        __syncthreads();
    }
}

// ---- tier-2: exact fp64 rescore; smallest index within DELTA (proven round 5) ----
__global__ __launch_bounds__(256)
void rescue_exact(const float* __restrict__ x, const float* __restrict__ codes,
                  const int* __restrict__ count, const int* __restrict__ rowlist,
                  float* __restrict__ out_q, float* __restrict__ out_i) {
    __shared__ float  xrow[D];
    __shared__ double dbuf[C];
    __shared__ double rmin[256];
    __shared__ int    ridx[256];
    const int t = threadIdx.x;
    const int n = *count;
    for (int idx = blockIdx.x; idx < n; idx += gridDim.x) {
        const int row = rowlist[idx];
        __syncthreads();
        xrow[t] = x[(size_t)row * D + t];
        __syncthreads();
        double lmin = 1e300;
        #pragma unroll
        for (int j = 0; j < 4; ++j) {
            const int c = 4 * t + j;
            const float* cp = codes + (size_t)c * D;
            double s = 0.0;
            for (int k = 0; k < D; k += 4) {
                float4 cv = *(const float4*)(cp + k);
                double d0 = (double)xrow[k+0] - (double)cv.x;
                double d1 = (double)xrow[k+1] - (double)cv.y;
                double d2 = (double)xrow[k+2] - (double)cv.z;
                double d3 = (double)xrow[k+3] - (double)cv.w;
                s += d0*d0 + d1*d1 + d2*d2 + d3*d3;
            }
            dbuf[c] = s;
            lmin = fmin(lmin, s);
        }
        rmin[t] = lmin;
        __syncthreads();
        for (int sft = 128; sft > 0; sft >>= 1) {
            if (t < sft) rmin[t] = fmin(rmin[t], rmin[t + sft]);
            __syncthreads();
        }
        const double dstar = rmin[0];
        int lidx = INT_MAX;
        #pragma unroll
        for (int j = 0; j < 4; ++j) {
            const int c = 4 * t + j;
            if (dbuf[c] < dstar + DELTA && c < lidx) lidx = c;
        }
        ridx[t] = lidx;
        __syncthreads();
        for (int sft = 128; sft > 0; sft >>= 1) {
            if (t < sft) ridx[t] = min(ridx[t], ridx[t + sft]);
            __syncthreads();
        }
        const int winc = ridx[0];
        if (t == 0) out_i[row] = (float)winc;
        if (t < 64) {
            float4 cv = ((const float4*)(codes + (size_t)winc * D))[t];
            ((float4*)(out_q + (size_t)row * D))[t] = cv;
        }
        __syncthreads();
    }
}

extern "C" void kernel_launch(void* const* d_in, const int* in_sizes, int n_in,
                              void* d_out, int out_size, void* d_ws, size_t ws_size,
                              hipStream_t stream) {
    const float* x     = (const float*)d_in[0];
    const float* codes = (const float*)d_in[1];
    const int N = in_sizes[0] / D;                 // 65536

    char* ws = (char*)d_ws;
    float*    cnorm   = (float*)ws;                       ws += C * 4;              // 4 KB
    float*    codes_t = (float*)ws;                       ws += (size_t)D * C * 4;  // 1 MB
    _Float16* codes_h = (_Float16*)ws;                    ws += (size_t)C * D * 2;  // 512 KB (tiled)
    int*      count1  = (int*)ws;                         ws += 16;
    int*      count2  = (int*)ws;                         ws += 16;
    int*      rowlist1 = (int*)ws;                        ws += (size_t)N * 4;
    int*      rowlist2 = (int*)ws;

    float* out_q = (float*)d_out;
    float* out_i = out_q + (size_t)N * D;

    prep<<<C / 4, 256, 0, stream>>>(codes, cnorm, codes_h, codes_t, count1, count2);
    codebook_mfma<<<N / 64, 256, 0, stream>>>(x, codes_h, codes, cnorm,
                                              out_q, out_i, count1, rowlist1);
    rescue32<<<256, 256, 0, stream>>>(x, codes, codes_t, cnorm, count1, rowlist1,
                                      out_q, out_i, count2, rowlist2);
    rescue_exact<<<128, 256, 0, stream>>>(x, codes, count2, rowlist2, out_q, out_i);
}

// Round 4
// 326.159 us; speedup vs baseline: 1.4432x; 1.2549x over previous
//
#include <hip/hip_runtime.h>
#include <float.h>
#include <limits.h>

// Codebook / VQ: x [65536][256] fp32, codes [1024][256] fp32
// out: quantized [65536][256] fp32, then indices [65536] as fp32 values.
// Tiered: fp16 MFMA GEMM argmin (all rows) -> fp32 rescue (gap<EPS1 rows)
//        -> fp64+DELTA smallest-index rescue (gap<EPS2 rows, proven round 5).
// Round 4: SWAPPED-OPERAND restructure. mfma(codes_frag, x_frag) puts
// col=lane&15 = x-row, so each lane sees candidates of ONE row only ->
// per-lane top-2 state drops 32 regs -> 2 regs. Wave holds its 16 x-rows
// fully in registers (32 VGPRs fp16); codes stream from L2-resident tiled
// codes_h. Zero LDS, zero syncthreads in the main kernel. This removes the
// register-allocator collision that caused spills in rounds 1-3 (FETCH
// 469/237 MB of scratch; VGPR forced to 64/84).
#define D     256
#define C     1024
#define EPS1  0.45f     // fp16-MFMA gap flag: 0.3 (fp16 err) + 0.125 (key truncation) + slack
#define EPS2  0.02f     // fp32 gap flag (proven)
#define DELTA 1.0e-4    // np ulp-collision window on exact fp64 distances
#define BR    16        // rows per batch in fp32 rescue

typedef _Float16 half8 __attribute__((ext_vector_type(8)));
typedef _Float16 half4_t __attribute__((ext_vector_type(4)));
typedef float v4f __attribute__((ext_vector_type(4)));

static __device__ __forceinline__ unsigned umin_(unsigned a, unsigned b) { return a < b ? a : b; }
static __device__ __forceinline__ unsigned umax_(unsigned a, unsigned b) { return a > b ? a : b; }

// prep: cnorm fp32 (+biased copy), codes -> fp16 TILED copy, codes -> fp32
// transpose, zero counters.
// Tiled fp16 layout (HW-verified rounds 2-3): value codes[c][k] at
//   codes_h[(c>>4)*4096 + (k>>5)*512 + (((k>>3)&3)*16 + (c&15))*8 + (k&7)]
// => the fragment for (tile t, kc) is codes_h + t*4096 + kc*512 + lane*8:
// one contiguous 1KB segment per wave-load; serves as the MFMA A-operand
// (lane l: row = l&15 = code-in-tile, k = (l>>4)*8 + j).
__global__ __launch_bounds__(256)
void prep(const float* __restrict__ codes, float* __restrict__ cnorm,
          float* __restrict__ cnormb,
          _Float16* __restrict__ codes_h, float* __restrict__ codes_t,
          int* __restrict__ count1, int* __restrict__ count2) {
    if (blockIdx.x == 0 && threadIdx.x == 0) { *count1 = 0; *count2 = 0; }
    int c    = (blockIdx.x * blockDim.x + threadIdx.x) >> 6;   // 0..1023, one code per wave
    int lane = threadIdx.x & 63;
    float4 v = ((const float4*)(codes + (size_t)c * D))[lane]; // k = 4*lane..4*lane+3
    // fp16 tiled write (4 halfs stay inside one 8-elem group: (4*lane)&7 in {0,4})
    half4_t h; h[0] = (_Float16)v.x; h[1] = (_Float16)v.y; h[2] = (_Float16)v.z; h[3] = (_Float16)v.w;
    {
        int kc   = lane >> 3;            // (4*lane)>>5
        int quad = (lane >> 1) & 3;      // ((4*lane)>>3)&3
        int e    = (lane & 1) * 4;       // (4*lane)&7
        size_t off = (size_t)(c >> 4) * 4096 + kc * 512 + (quad * 16 + (c & 15)) * 8 + e;
        *(half4_t*)(codes_h + off) = h;
    }
    // fp32 transpose codes_t[k][c]
    codes_t[(size_t)(4*lane+0) * C + c] = v.x;
    codes_t[(size_t)(4*lane+1) * C + c] = v.y;
    codes_t[(size_t)(4*lane+2) * C + c] = v.z;
    codes_t[(size_t)(4*lane+3) * C + c] = v.w;
    float s = v.x * v.x + v.y * v.y + v.z * v.z + v.w * v.w;
    #pragma unroll
    for (int off = 32; off >= 1; off >>= 1) s += __shfl_xor(s, off, 64);
    if (lane == 0) { cnorm[c] = s; cnormb[c] = s + 1024.0f; }
}

// ---- main: fp16 MFMA distance argmin, 64 rows/block, 16 rows per wave ----
// mfma(A=codes_tile[16c x 32k], B=x_frag[32k x 16rows]) -> C[code][xrow],
// lane layout col=lane&15 = xrow, row=(lane>>4)*4+reg = code-in-tile.
// Packed key: score = dist - ||x||^2 + 1024 > 0 (||x||^2 < ~400), IEEE bits
// order as uints; low 10 mantissa bits replaced by code index => u32 min is
// lexicographic (trunc score, index). Truncation err < 0.125 inside EPS1.
__global__ __launch_bounds__(256, 4)
void codebook_mfma(const float* __restrict__ x, const _Float16* __restrict__ codes_h,
                   const float* __restrict__ codes, const float* __restrict__ cnormb,
                   float* __restrict__ out_q, float* __restrict__ out_i,
                   int* __restrict__ count1, int* __restrict__ rowlist1) {
    const int tid  = threadIdx.x;
    const int wy   = tid >> 6, lane = tid & 63;
    const int quad = lane >> 4, l15 = lane & 15;
    const int row0 = blockIdx.x * 64;
    const int myrow = row0 + wy * 16 + l15;   // the ONE x-row this lane scores

    // this wave's 16 x-rows -> registers as fp16 B-fragments (32 VGPRs)
    const float* xp = x + (size_t)myrow * D + quad * 8;
    half8 xf[8];
    #pragma unroll
    for (int kc = 0; kc < 8; ++kc) {
        float4 a = *(const float4*)(xp + kc * 32);
        float4 b = *(const float4*)(xp + kc * 32 + 4);
        half8 h;
        h[0]=(_Float16)a.x; h[1]=(_Float16)a.y; h[2]=(_Float16)a.z; h[3]=(_Float16)a.w;
        h[4]=(_Float16)b.x; h[5]=(_Float16)b.y; h[6]=(_Float16)b.z; h[7]=(_Float16)b.w;
        xf[kc] = h;
    }

    unsigned K1 = 0xFFFFFFFFu, K2 = 0xFFFFFFFFu;   // per-lane top-2 for myrow
    const unsigned colq = (unsigned)(quad * 4);    // code sub-index base

    for (int ct = 0; ct < 16; ++ct) {              // 16 chunks of 64 codes
        v4f acc[4];
        #pragma unroll
        for (int t = 0; t < 4; ++t) acc[t] = (v4f){0.f, 0.f, 0.f, 0.f};

        const _Float16* bt = codes_h + (size_t)ct * 16384 + lane * 8;
        #pragma unroll
        for (int kc = 0; kc < 8; ++kc) {
            half8 b0 = *(const half8*)(bt + kc * 512);
            half8 b1 = *(const half8*)(bt + 4096  + kc * 512);
            half8 b2 = *(const half8*)(bt + 8192  + kc * 512);
            half8 b3 = *(const half8*)(bt + 12288 + kc * 512);
            acc[0] = __builtin_amdgcn_mfma_f32_16x16x32_f16(b0, xf[kc], acc[0], 0, 0, 0);
            acc[1] = __builtin_amdgcn_mfma_f32_16x16x32_f16(b1, xf[kc], acc[1], 0, 0, 0);
            acc[2] = __builtin_amdgcn_mfma_f32_16x16x32_f16(b2, xf[kc], acc[2], 0, 0, 0);
            acc[3] = __builtin_amdgcn_mfma_f32_16x16x32_f16(b3, xf[kc], acc[3], 0, 0, 0);
        }

        #pragma unroll
        for (int t = 0; t < 4; ++t) {
            const int cbase = ct * 64 + t * 16;               // multiple of 16
            float4 cn = *(const float4*)(cnormb + cbase + colq);
            const unsigned base = (unsigned)cbase | colq;     // disjoint bits
            unsigned k0 = (__float_as_uint(fmaf(-2.0f, acc[t][0], cn.x)) & 0xFFFFFC00u) | base;
            unsigned k1 = (__float_as_uint(fmaf(-2.0f, acc[t][1], cn.y)) & 0xFFFFFC00u) | base | 1u;
            unsigned k2 = (__float_as_uint(fmaf(-2.0f, acc[t][2], cn.z)) & 0xFFFFFC00u) | base | 2u;
            unsigned k3 = (__float_as_uint(fmaf(-2.0f, acc[t][3], cn.w)) & 0xFFFFFC00u) | base | 3u;
            // top-2 of 4 (network), then merge into running top-2
            unsigned lo01 = umin_(k0, k1), hi01 = umax_(k0, k1);
            unsigned lo23 = umin_(k2, k3), hi23 = umax_(k2, k3);
            unsigned best = umin_(lo01, lo23);
            unsigned mid  = umax_(lo01, lo23);
            unsigned sec  = umin_(umin_(hi01, hi23), mid);
            unsigned tt   = umax_(K1, best);
            K2 = umin_(umin_(K2, sec), tt);
            K1 = umin_(K1, best);
        }
    }

    // merge the 4 quads (lanes l15, l15+16, l15+32, l15+48 hold the same row)
    #pragma unroll
    for (int off = 16; off < 64; off <<= 1) {
        unsigned o1 = (unsigned)__shfl_xor((int)K1, off, 64);
        unsigned o2 = (unsigned)__shfl_xor((int)K2, off, 64);
        unsigned tt = umax_(K1, o1);
        K2 = umin_(umin_(K2, o2), tt);
        K1 = umin_(K1, o1);
    }

    // winner + gap flag (quad 0 lanes own the 16 rows)
    if (lane < 16) {
        unsigned widx = K1 & 0x3FFu;
        out_i[myrow] = (float)widx;
        float g1 = __uint_as_float(K1 & 0xFFFFFC00u);
        float g2 = __uint_as_float(K2 & 0xFFFFFC00u);
        if (g2 - g1 < EPS1) {
            int s = atomicAdd(count1, 1);
            rowlist1[s] = myrow;
        }
    }

    // gather quantized rows: wave writes its own 16 rows, fully coalesced
    const float4* c4 = (const float4*)codes;
    float4* q4 = (float4*)out_q + (size_t)(row0 + wy * 16) * 64;
    #pragma unroll
    for (int r = 0; r < 16; ++r) {
        int wi = __shfl((int)K1, r, 64) & 0x3FF;   // lane r holds row r's winner
        q4[(size_t)r * 64 + lane] = c4[(size_t)wi * 64 + lane];
    }
}

// ---- tier-1: fp32 rescore of flagged rows, BR rows/block share codes stream ----
__global__ __launch_bounds__(256)
void rescue32(const float* __restrict__ x, const float* __restrict__ codes,
              const float* __restrict__ codes_t, const float* __restrict__ cnorm,
              const int* __restrict__ count1, const int* __restrict__ rowlist1,
              float* __restrict__ out_q, float* __restrict__ out_i,
              int* __restrict__ count2, int* __restrict__ rowlist2) {
    __shared__ __align__(16) float xr[BR * D];   // 16 KB
    __shared__ int rows_s[BR];
    __shared__ int winc_s[BR];
    __shared__ float wm1[4], wm2[4];
    __shared__ int wi_[4];
    const int t = threadIdx.x;
    const int n1 = *count1;
    if (n1 == 0) return;
    const int nb = (n1 + BR - 1) / BR;
    const float4* ct4 = (const float4*)codes_t;  // [k][c/4]

    for (int b = blockIdx.x; b < nb; b += gridDim.x) {
        __syncthreads();
        if (t < BR) {
            int idx = b * BR + t;
            if (idx >= n1) idx = n1 - 1;           // duplicate tail rows (benign)
            rows_s[t] = rowlist1[idx];
        }
        __syncthreads();
        #pragma unroll
        for (int p = 0; p < BR * 64 / 256; ++p) {  // 4 iters
            int flat = p * 256 + t;
            int r = flat >> 6, q = flat & 63;
            ((float4*)xr)[r * 64 + q] = ((const float4*)x)[(size_t)rows_s[r] * 64 + q];
        }
        __syncthreads();

        float acc[BR][4];
        #pragma unroll
        for (int r = 0; r < BR; ++r)
            #pragma unroll
            for (int j = 0; j < 4; ++j) acc[r][j] = 0.f;

        for (int k = 0; k < D; k += 4) {
            float4 cv0 = ct4[(size_t)(k+0) * 256 + t];
            float4 cv1 = ct4[(size_t)(k+1) * 256 + t];
            float4 cv2 = ct4[(size_t)(k+2) * 256 + t];
            float4 cv3 = ct4[(size_t)(k+3) * 256 + t];
            #pragma unroll
            for (int r = 0; r < BR; ++r) {
                float4 xv = *(const float4*)&xr[r * D + k];
                acc[r][0] = fmaf(xv.x, cv0.x, acc[r][0]);
                acc[r][1] = fmaf(xv.x, cv0.y, acc[r][1]);
                acc[r][2] = fmaf(xv.x, cv0.z, acc[r][2]);
                acc[r][3] = fmaf(xv.x, cv0.w, acc[r][3]);
                acc[r][0] = fmaf(xv.y, cv1.x, acc[r][0]);
                acc[r][1] = fmaf(xv.y, cv1.y, acc[r][1]);
                acc[r][2] = fmaf(xv.y, cv1.z, acc[r][2]);
                acc[r][3] = fmaf(xv.y, cv1.w, acc[r][3]);
                acc[r][0] = fmaf(xv.z, cv2.x, acc[r][0]);
                acc[r][1] = fmaf(xv.z, cv2.y, acc[r][1]);
                acc[r][2] = fmaf(xv.z, cv2.z, acc[r][2]);
                acc[r][3] = fmaf(xv.z, cv2.w, acc[r][3]);
                acc[r][0] = fmaf(xv.w, cv3.x, acc[r][0]);
                acc[r][1] = fmaf(xv.w, cv3.y, acc[r][1]);
                acc[r][2] = fmaf(xv.w, cv3.z, acc[r][2]);
                acc[r][3] = fmaf(xv.w, cv3.w, acc[r][3]);
            }
        }

        float cn0 = cnorm[4*t+0], cn1 = cnorm[4*t+1], cn2 = cnorm[4*t+2], cn3 = cnorm[4*t+3];
        for (int r = 0; r < BR; ++r) {
            float s0 = fmaf(-2.f, acc[r][0], cn0);
            float s1 = fmaf(-2.f, acc[r][1], cn1);
            float s2 = fmaf(-2.f, acc[r][2], cn2);
            float s3 = fmaf(-2.f, acc[r][3], cn3);
            float lm1 = s0; int li = 4*t;
            float lm2 = FLT_MAX;
            if (s1 < lm1) { lm2 = lm1; lm1 = s1; li = 4*t+1; } else lm2 = s1;
            if (s2 < lm1) { lm2 = lm1; lm1 = s2; li = 4*t+2; } else lm2 = fminf(lm2, s2);
            if (s3 < lm1) { lm2 = lm1; lm1 = s3; li = 4*t+3; } else lm2 = fminf(lm2, s3);
            // wave-wide butterfly merge (64 lanes all hold candidates of row r)
            #pragma unroll
            for (int off = 1; off < 64; off <<= 1) {
                float o1 = __shfl_xor(lm1, off, 64);
                float o2 = __shfl_xor(lm2, off, 64);
                int   oi = __shfl_xor(li,  off, 64);
                if (o1 < lm1 || (o1 == lm1 && oi < li)) { lm2 = fminf(lm1, o2); lm1 = o1; li = oi; }
                else lm2 = fminf(lm2, o1);
            }
            // cross-wave (4 waves) via LDS: wave w writes slot, then merge by t==0
            const int w = t >> 6;
            if ((t & 63) == 0) { wm1[w] = lm1; wm2[w] = lm2; wi_[w] = li; }
            __syncthreads();
            if (t == 0) {
                float b1 = wm1[0], b2 = wm2[0]; int bi = wi_[0];
                #pragma unroll
                for (int ww = 1; ww < 4; ++ww) {
                    float o1 = wm1[ww], o2 = wm2[ww]; int oi = wi_[ww];
                    if (o1 < b1 || (o1 == b1 && oi < bi)) { b2 = fminf(b1, o2); b1 = o1; bi = oi; }
                    else b2 = fminf(b2, o1);
                }
                const int rg = rows_s[r];
                out_i[rg] = (float)bi;
                winc_s[r] = bi;
                if (b2 - b1 < EPS2) {
                    int s = atomicAdd(count2, 1);
                    rowlist2[s] = rg;
                }
            }
            __syncthreads();
        }
        // gather quantized rows
        #pragma unroll
        for (int p = 0; p < BR * 64 / 256; ++p) {
            int flat = p * 256 + t;
            int r = flat >> 6, q = flat & 63;
            float4 v = ((const float4*)codes)[(size_t)winc_s[r] * 64 + q];
            ((float4*)out_q)[(size_t)rows_s[r] * 64 + q] = v;
        }
        __syncthreads();
    }
}

// ---- tier-2: exact fp64 rescore; smallest index within DELTA (proven round 5) ----
__global__ __launch_bounds__(256)
void rescue_exact(const float* __restrict__ x, const float* __restrict__ codes,
                  const int* __restrict__ count, const int* __restrict__ rowlist,
                  float* __restrict__ out_q, float* __restrict__ out_i) {
    __shared__ float  xrow[D];
    __shared__ double dbuf[C];
    __shared__ double rmin[256];
    __shared__ int    ridx[256];
    const int t = threadIdx.x;
    const int n = *count;
    for (int idx = blockIdx.x; idx < n; idx += gridDim.x) {
        const int row = rowlist[idx];
        __syncthreads();
        xrow[t] = x[(size_t)row * D + t];
        __syncthreads();
        double lmin = 1e300;
        #pragma unroll
        for (int j = 0; j < 4; ++j) {
            const int c = 4 * t + j;
            const float* cp = codes + (size_t)c * D;
            double s = 0.0;
            for (int k = 0; k < D; k += 4) {
                float4 cv = *(const float4*)(cp + k);
                double d0 = (double)xrow[k+0] - (double)cv.x;
                double d1 = (double)xrow[k+1] - (double)cv.y;
                double d2 = (double)xrow[k+2] - (double)cv.z;
                double d3 = (double)xrow[k+3] - (double)cv.w;
                s += d0*d0 + d1*d1 + d2*d2 + d3*d3;
            }
            dbuf[c] = s;
            lmin = fmin(lmin, s);
        }
        rmin[t] = lmin;
        __syncthreads();
        for (int sft = 128; sft > 0; sft >>= 1) {
            if (t < sft) rmin[t] = fmin(rmin[t], rmin[t + sft]);
            __syncthreads();
        }
        const double dstar = rmin[0];
        int lidx = INT_MAX;
        #pragma unroll
        for (int j = 0; j < 4; ++j) {
            const int c = 4 * t + j;
            if (dbuf[c] < dstar + DELTA && c < lidx) lidx = c;
        }
        ridx[t] = lidx;
        __syncthreads();
        for (int sft = 128; sft > 0; sft >>= 1) {
            if (t < sft) ridx[t] = min(ridx[t], ridx[t + sft]);
            __syncthreads();
        }
        const int winc = ridx[0];
        if (t == 0) out_i[row] = (float)winc;
        if (t < 64) {
            float4 cv = ((const float4*)(codes + (size_t)winc * D))[t];
            ((float4*)(out_q + (size_t)row * D))[t] = cv;
        }
        __syncthreads();
    }
}

extern "C" void kernel_launch(void* const* d_in, const int* in_sizes, int n_in,
                              void* d_out, int out_size, void* d_ws, size_t ws_size,
                              hipStream_t stream) {
    const float* x     = (const float*)d_in[0];
    const float* codes = (const float*)d_in[1];
    const int N = in_sizes[0] / D;                 // 65536

    char* ws = (char*)d_ws;
    float*    cnorm   = (float*)ws;                       ws += C * 4;              // 4 KB
    float*    cnormb  = (float*)ws;                       ws += C * 4;              // 4 KB (biased +1024)
    float*    codes_t = (float*)ws;                       ws += (size_t)D * C * 4;  // 1 MB
    _Float16* codes_h = (_Float16*)ws;                    ws += (size_t)C * D * 2;  // 512 KB (tiled)
    int*      count1  = (int*)ws;                         ws += 16;
    int*      count2  = (int*)ws;                         ws += 16;
    int*      rowlist1 = (int*)ws;                        ws += (size_t)N * 4;
    int*      rowlist2 = (int*)ws;

    float* out_q = (float*)d_out;
    float* out_i = out_q + (size_t)N * D;

    prep<<<C / 4, 256, 0, stream>>>(codes, cnorm, cnormb, codes_h, codes_t, count1, count2);
    codebook_mfma<<<N / 64, 256, 0, stream>>>(x, codes_h, codes, cnormb,
                                              out_q, out_i, count1, rowlist1);
    rescue32<<<1024, 256, 0, stream>>>(x, codes, codes_t, cnorm, count1, rowlist1,
                                       out_q, out_i, count2, rowlist2);
    rescue_exact<<<256, 256, 0, stream>>>(x, codes, count2, rowlist2, out_q, out_i);
}

// Round 5
// 230.098 us; speedup vs baseline: 2.0457x; 1.4175x over previous
//
#include <hip/hip_runtime.h>
#include <float.h>
#include <limits.h>

// Codebook / VQ: x [65536][256] fp32, codes [1024][256] fp32
// out: quantized [65536][256] fp32, then indices [65536] as fp32 values.
// Tiered: fp16 MFMA GEMM argmin (all rows) -> fp32 rescue (gap<EPS1 rows)
//        -> fp64+DELTA smallest-index rescue (gap<EPS2 rows, proven round 5).
// Round 5:
//  (a) codebook_mfma: double-buffered LDS staging of codes via
//      global_load_lds (2x16KB chunks of 32 codes). Round-4 counters showed
//      pure L2-load latency (MfmaUtil 12.5, VALUBusy 14.5, HBM 11%): compiler
//      drained vmcnt before every MFMA group. 2-phase pipeline keeps loads in
//      flight across the compute phase.
//  (b) rescue32: BR 16->8 (acc 32 regs, was 64 vs VGPR_Count=64 -> spill) and
//      batched reduction: all rows' in-wave butterflies in registers, ONE
//      cross-wave LDS merge (5 barriers/batch, was 34). n1-limited latency.
#define D     256
#define C     1024
#define EPS1  0.45f     // fp16-MFMA gap flag: 0.3 (fp16 err) + 0.125 (key truncation) + slack
#define EPS2  0.02f     // fp32 gap flag (proven)
#define DELTA 1.0e-4    // np ulp-collision window on exact fp64 distances
#define BR    8         // rows per batch in fp32 rescue

typedef _Float16 half8 __attribute__((ext_vector_type(8)));
typedef _Float16 half4_t __attribute__((ext_vector_type(4)));
typedef float v4f __attribute__((ext_vector_type(4)));

typedef const __attribute__((address_space(1))) void g_void;
typedef __attribute__((address_space(3))) void l_void;

static __device__ __forceinline__ unsigned umin_(unsigned a, unsigned b) { return a < b ? a : b; }
static __device__ __forceinline__ unsigned umax_(unsigned a, unsigned b) { return a > b ? a : b; }

// prep: cnorm fp32 (+biased copy), codes -> fp16 TILED copy, codes -> fp32
// transpose, zero counters.
// Tiled fp16 layout (HW-verified rounds 2-4): value codes[c][k] at
//   codes_h[(c>>4)*4096 + (k>>5)*512 + (((k>>3)&3)*16 + (c&15))*8 + (k&7)]
// => the fragment for (tile t, kc) is codes_h + t*4096 + kc*512 + lane*8:
// one contiguous 1KB segment per wave-load; serves as the MFMA A-operand
// (lane l: row = l&15 = code-in-tile, k = (l>>4)*8 + j).
__global__ __launch_bounds__(256)
void prep(const float* __restrict__ codes, float* __restrict__ cnorm,
          float* __restrict__ cnormb,
          _Float16* __restrict__ codes_h, float* __restrict__ codes_t,
          int* __restrict__ count1, int* __restrict__ count2) {
    if (blockIdx.x == 0 && threadIdx.x == 0) { *count1 = 0; *count2 = 0; }
    int c    = (blockIdx.x * blockDim.x + threadIdx.x) >> 6;   // 0..1023, one code per wave
    int lane = threadIdx.x & 63;
    float4 v = ((const float4*)(codes + (size_t)c * D))[lane]; // k = 4*lane..4*lane+3
    // fp16 tiled write (4 halfs stay inside one 8-elem group: (4*lane)&7 in {0,4})
    half4_t h; h[0] = (_Float16)v.x; h[1] = (_Float16)v.y; h[2] = (_Float16)v.z; h[3] = (_Float16)v.w;
    {
        int kc   = lane >> 3;            // (4*lane)>>5
        int quad = (lane >> 1) & 3;      // ((4*lane)>>3)&3
        int e    = (lane & 1) * 4;       // (4*lane)&7
        size_t off = (size_t)(c >> 4) * 4096 + kc * 512 + (quad * 16 + (c & 15)) * 8 + e;
        *(half4_t*)(codes_h + off) = h;
    }
    // fp32 transpose codes_t[k][c]
    codes_t[(size_t)(4*lane+0) * C + c] = v.x;
    codes_t[(size_t)(4*lane+1) * C + c] = v.y;
    codes_t[(size_t)(4*lane+2) * C + c] = v.z;
    codes_t[(size_t)(4*lane+3) * C + c] = v.w;
    float s = v.x * v.x + v.y * v.y + v.z * v.z + v.w * v.w;
    #pragma unroll
    for (int off = 32; off >= 1; off >>= 1) s += __shfl_xor(s, off, 64);
    if (lane == 0) { cnorm[c] = s; cnormb[c] = s + 1024.0f; }
}

// ---- main: fp16 MFMA distance argmin, 64 rows/block, 16 rows per wave ----
// mfma(A=codes_tile[16c x 32k], B=x_frag[32k x 16rows]) -> C[code][xrow],
// lane layout col=lane&15 = xrow, row=(lane>>4)*4+reg = code-in-tile.
// Codes double-buffered in LDS: chunk = 32 codes (2 tiles) = 16 KB, staged
// with global_load_lds (linear dest = wave-uniform base + lane*16, matching
// the tiled codes_h layout exactly). One barrier per chunk.
__global__ __launch_bounds__(256, 4)
void codebook_mfma(const float* __restrict__ x, const _Float16* __restrict__ codes_h,
                   const float* __restrict__ codes, const float* __restrict__ cnormb,
                   float* __restrict__ out_q, float* __restrict__ out_i,
                   int* __restrict__ count1, int* __restrict__ rowlist1) {
    __shared__ __align__(16) _Float16 Bs[2][8192];   // 2 x 16 KB: 32 codes x 256 k

    const int tid  = threadIdx.x;
    const int wy   = tid >> 6, lane = tid & 63;
    const int quad = lane >> 4, l15 = lane & 15;
    const int row0 = blockIdx.x * 64;
    const int myrow = row0 + wy * 16 + l15;   // the ONE x-row this lane scores

    // stage chunk 0 (16 KB): 4 x 16B per thread, linear
    {
        const char* g = (const char*)codes_h;
        char* l = (char*)&Bs[0][0];
        #pragma unroll
        for (int p = 0; p < 4; ++p) {
            const int off = (p * 256 + tid) * 16;
            __builtin_amdgcn_global_load_lds((g_void*)(g + off), (l_void*)(l + off), 16, 0, 0);
        }
    }

    // this wave's 16 x-rows -> registers as fp16 B-fragments (32 VGPRs)
    // (global loads overlap with the staging DMA above)
    const float* xp = x + (size_t)myrow * D + quad * 8;
    half8 xf[8];
    #pragma unroll
    for (int kc = 0; kc < 8; ++kc) {
        float4 a = *(const float4*)(xp + kc * 32);
        float4 b = *(const float4*)(xp + kc * 32 + 4);
        half8 h;
        h[0]=(_Float16)a.x; h[1]=(_Float16)a.y; h[2]=(_Float16)a.z; h[3]=(_Float16)a.w;
        h[4]=(_Float16)b.x; h[5]=(_Float16)b.y; h[6]=(_Float16)b.z; h[7]=(_Float16)b.w;
        xf[kc] = h;
    }

    unsigned K1 = 0xFFFFFFFFu, K2 = 0xFFFFFFFFu;   // per-lane top-2 for myrow
    __syncthreads();   // chunk 0 staged (syncthreads drains vmcnt+lgkmcnt)

    for (int ct = 0; ct < 32; ++ct) {              // 32 chunks of 32 codes
        const int cur = ct & 1;
        if (ct < 31) {                             // prefetch next chunk
            const char* g = (const char*)codes_h + (size_t)(ct + 1) * 16384;
            char* l = (char*)&Bs[cur ^ 1][0];
            #pragma unroll
            for (int p = 0; p < 4; ++p) {
                const int off = (p * 256 + tid) * 16;
                __builtin_amdgcn_global_load_lds((g_void*)(g + off), (l_void*)(l + off), 16, 0, 0);
            }
        }

        const _Float16* bt = &Bs[cur][0] + lane * 8;
        v4f acc0 = (v4f){0.f, 0.f, 0.f, 0.f};
        v4f acc1 = (v4f){0.f, 0.f, 0.f, 0.f};
        #pragma unroll
        for (int kc = 0; kc < 8; ++kc) {
            half8 b0 = *(const half8*)(bt + kc * 512);
            half8 b1 = *(const half8*)(bt + 4096 + kc * 512);
            acc0 = __builtin_amdgcn_mfma_f32_16x16x32_f16(b0, xf[kc], acc0, 0, 0, 0);
            acc1 = __builtin_amdgcn_mfma_f32_16x16x32_f16(b1, xf[kc], acc1, 0, 0, 0);
        }

        // score = (cnorm + 1024) - 2*dot (positive); pack trunc-score|index
        const int cb = ct * 32 + quad * 4;
        float4 cn0 = *(const float4*)(cnormb + cb);
        float4 cn1 = *(const float4*)(cnormb + cb + 16);
        {
            const unsigned base = (unsigned)cb;
            unsigned k0 = (__float_as_uint(fmaf(-2.0f, acc0[0], cn0.x)) & 0xFFFFFC00u) | base;
            unsigned k1 = (__float_as_uint(fmaf(-2.0f, acc0[1], cn0.y)) & 0xFFFFFC00u) | (base + 1u);
            unsigned k2 = (__float_as_uint(fmaf(-2.0f, acc0[2], cn0.z)) & 0xFFFFFC00u) | (base + 2u);
            unsigned k3 = (__float_as_uint(fmaf(-2.0f, acc0[3], cn0.w)) & 0xFFFFFC00u) | (base + 3u);
            unsigned lo01 = umin_(k0, k1), hi01 = umax_(k0, k1);
            unsigned lo23 = umin_(k2, k3), hi23 = umax_(k2, k3);
            unsigned best = umin_(lo01, lo23);
            unsigned mid  = umax_(lo01, lo23);
            unsigned sec  = umin_(umin_(hi01, hi23), mid);
            unsigned tt   = umax_(K1, best);
            K2 = umin_(umin_(K2, sec), tt);
            K1 = umin_(K1, best);
        }
        {
            const unsigned base = (unsigned)(cb + 16);
            unsigned k0 = (__float_as_uint(fmaf(-2.0f, acc1[0], cn1.x)) & 0xFFFFFC00u) | base;
            unsigned k1 = (__float_as_uint(fmaf(-2.0f, acc1[1], cn1.y)) & 0xFFFFFC00u) | (base + 1u);
            unsigned k2 = (__float_as_uint(fmaf(-2.0f, acc1[2], cn1.z)) & 0xFFFFFC00u) | (base + 2u);
            unsigned k3 = (__float_as_uint(fmaf(-2.0f, acc1[3], cn1.w)) & 0xFFFFFC00u) | (base + 3u);
            unsigned lo01 = umin_(k0, k1), hi01 = umax_(k0, k1);
            unsigned lo23 = umin_(k2, k3), hi23 = umax_(k2, k3);
            unsigned best = umin_(lo01, lo23);
            unsigned mid  = umax_(lo01, lo23);
            unsigned sec  = umin_(umin_(hi01, hi23), mid);
            unsigned tt   = umax_(K1, best);
            K2 = umin_(umin_(K2, sec), tt);
            K1 = umin_(K1, best);
        }
        // one barrier per chunk: reads of Bs[cur] done before it is re-staged
        __syncthreads();
    }

    // merge the 4 quads (lanes l15, l15+16, l15+32, l15+48 hold the same row)
    #pragma unroll
    for (int off = 16; off < 64; off <<= 1) {
        unsigned o1 = (unsigned)__shfl_xor((int)K1, off, 64);
        unsigned o2 = (unsigned)__shfl_xor((int)K2, off, 64);
        unsigned tt = umax_(K1, o1);
        K2 = umin_(umin_(K2, o2), tt);
        K1 = umin_(K1, o1);
    }

    // winner + gap flag (quad 0 lanes own the 16 rows)
    if (lane < 16) {
        unsigned widx = K1 & 0x3FFu;
        out_i[myrow] = (float)widx;
        float g1 = __uint_as_float(K1 & 0xFFFFFC00u);
        float g2 = __uint_as_float(K2 & 0xFFFFFC00u);
        if (g2 - g1 < EPS1) {
            int s = atomicAdd(count1, 1);
            rowlist1[s] = myrow;
        }
    }

    // gather quantized rows: wave writes its own 16 rows, fully coalesced
    const float4* c4 = (const float4*)codes;
    float4* q4 = (float4*)out_q + (size_t)(row0 + wy * 16) * 64;
    #pragma unroll
    for (int r = 0; r < 16; ++r) {
        int wi = __shfl((int)K1, r, 64) & 0x3FF;   // lane r holds row r's winner
        q4[(size_t)r * 64 + lane] = c4[(size_t)wi * 64 + lane];
    }
}

// ---- tier-1: fp32 rescore of flagged rows, BR rows/block share codes stream ----
// All rows' wave-level butterflies run in registers (no barriers); single
// cross-wave LDS merge per batch.
__global__ __launch_bounds__(256)
void rescue32(const float* __restrict__ x, const float* __restrict__ codes,
              const float* __restrict__ codes_t, const float* __restrict__ cnorm,
              const int* __restrict__ count1, const int* __restrict__ rowlist1,
              float* __restrict__ out_q, float* __restrict__ out_i,
              int* __restrict__ count2, int* __restrict__ rowlist2) {
    __shared__ __align__(16) float xr[BR][D];    // 8 KB
    __shared__ int rows_s[BR];
    __shared__ int winc_s[BR];
    __shared__ float wm1[BR][4], wm2[BR][4];
    __shared__ int wi_[BR][4];
    const int t = threadIdx.x;
    const int w = t >> 6, lane = t & 63;
    const int n1 = *count1;
    if (n1 == 0) return;
    const int nb = (n1 + BR - 1) / BR;
    const float4* ct4 = (const float4*)codes_t;  // [k][c/4]

    for (int b = blockIdx.x; b < nb; b += gridDim.x) {
        __syncthreads();
        if (t < BR) {
            int idx = b * BR + t;
            if (idx >= n1) idx = n1 - 1;           // duplicate tail rows (benign)
            rows_s[t] = rowlist1[idx];
        }
        __syncthreads();
        #pragma unroll
        for (int p = 0; p < BR * 64 / 256; ++p) {  // 2 iters
            int flat = p * 256 + t;
            int r = flat >> 6, q = flat & 63;
            ((float4*)&xr[r][0])[q] = ((const float4*)x)[(size_t)rows_s[r] * 64 + q];
        }
        __syncthreads();

        float acc[BR][4];                          // 32 VGPRs: fits, no spill
        #pragma unroll
        for (int r = 0; r < BR; ++r)
            #pragma unroll
            for (int j = 0; j < 4; ++j) acc[r][j] = 0.f;

        for (int k = 0; k < D; k += 4) {
            float4 cv0 = ct4[(size_t)(k+0) * 256 + t];
            float4 cv1 = ct4[(size_t)(k+1) * 256 + t];
            float4 cv2 = ct4[(size_t)(k+2) * 256 + t];
            float4 cv3 = ct4[(size_t)(k+3) * 256 + t];
            #pragma unroll
            for (int r = 0; r < BR; ++r) {
                float4 xv = *(const float4*)&xr[r][k];
                acc[r][0] = fmaf(xv.x, cv0.x, acc[r][0]);
                acc[r][1] = fmaf(xv.x, cv0.y, acc[r][1]);
                acc[r][2] = fmaf(xv.x, cv0.z, acc[r][2]);
                acc[r][3] = fmaf(xv.x, cv0.w, acc[r][3]);
                acc[r][0] = fmaf(xv.y, cv1.x, acc[r][0]);
                acc[r][1] = fmaf(xv.y, cv1.y, acc[r][1]);
                acc[r][2] = fmaf(xv.y, cv1.z, acc[r][2]);
                acc[r][3] = fmaf(xv.y, cv1.w, acc[r][3]);
                acc[r][0] = fmaf(xv.z, cv2.x, acc[r][0]);
                acc[r][1] = fmaf(xv.z, cv2.y, acc[r][1]);
                acc[r][2] = fmaf(xv.z, cv2.z, acc[r][2]);
                acc[r][3] = fmaf(xv.z, cv2.w, acc[r][3]);
                acc[r][0] = fmaf(xv.w, cv3.x, acc[r][0]);
                acc[r][1] = fmaf(xv.w, cv3.y, acc[r][1]);
                acc[r][2] = fmaf(xv.w, cv3.z, acc[r][2]);
                acc[r][3] = fmaf(xv.w, cv3.w, acc[r][3]);
            }
        }

        // per-thread top-2-of-4 + in-wave butterfly, all rows, no barriers
        float cn0 = cnorm[4*t+0], cn1 = cnorm[4*t+1], cn2 = cnorm[4*t+2], cn3 = cnorm[4*t+3];
        #pragma unroll
        for (int r = 0; r < BR; ++r) {
            float s0 = fmaf(-2.f, acc[r][0], cn0);
            float s1 = fmaf(-2.f, acc[r][1], cn1);
            float s2 = fmaf(-2.f, acc[r][2], cn2);
            float s3 = fmaf(-2.f, acc[r][3], cn3);
            float lm1 = s0; int li = 4*t;
            float lm2 = FLT_MAX;
            if (s1 < lm1) { lm2 = lm1; lm1 = s1; li = 4*t+1; } else lm2 = s1;
            if (s2 < lm1) { lm2 = lm1; lm1 = s2; li = 4*t+2; } else lm2 = fminf(lm2, s2);
            if (s3 < lm1) { lm2 = lm1; lm1 = s3; li = 4*t+3; } else lm2 = fminf(lm2, s3);
            #pragma unroll
            for (int off = 1; off < 64; off <<= 1) {
                float o1 = __shfl_xor(lm1, off, 64);
                float o2 = __shfl_xor(lm2, off, 64);
                int   oi = __shfl_xor(li,  off, 64);
                if (o1 < lm1 || (o1 == lm1 && oi < li)) { lm2 = fminf(lm1, o2); lm1 = o1; li = oi; }
                else lm2 = fminf(lm2, o1);
            }
            if (lane == 0) { wm1[r][w] = lm1; wm2[r][w] = lm2; wi_[r][w] = li; }
        }
        __syncthreads();
        if (t < BR) {
            float b1 = wm1[t][0], b2 = wm2[t][0]; int bi = wi_[t][0];
            #pragma unroll
            for (int ww = 1; ww < 4; ++ww) {
                float o1 = wm1[t][ww], o2 = wm2[t][ww]; int oi = wi_[t][ww];
                if (o1 < b1 || (o1 == b1 && oi < bi)) { b2 = fminf(b1, o2); b1 = o1; bi = oi; }
                else b2 = fminf(b2, o1);
            }
            const int rg = rows_s[t];
            out_i[rg] = (float)bi;
            winc_s[t] = bi;
            if (b2 - b1 < EPS2) {
                int s = atomicAdd(count2, 1);
                rowlist2[s] = rg;
            }
        }
        __syncthreads();
        // gather quantized rows
        #pragma unroll
        for (int p = 0; p < BR * 64 / 256; ++p) {
            int flat = p * 256 + t;
            int r = flat >> 6, q = flat & 63;
            float4 v = ((const float4*)codes)[(size_t)winc_s[r] * 64 + q];
            ((float4*)out_q)[(size_t)rows_s[r] * 64 + q] = v;
        }
        __syncthreads();
    }
}

// ---- tier-2: exact fp64 rescore; smallest index within DELTA (proven round 5) ----
__global__ __launch_bounds__(256)
void rescue_exact(const float* __restrict__ x, const float* __restrict__ codes,
                  const int* __restrict__ count, const int* __restrict__ rowlist,
                  float* __restrict__ out_q, float* __restrict__ out_i) {
    __shared__ float  xrow[D];
    __shared__ double dbuf[C];
    __shared__ double rmin[256];
    __shared__ int    ridx[256];
    const int t = threadIdx.x;
    const int n = *count;
    for (int idx = blockIdx.x; idx < n; idx += gridDim.x) {
        const int row = rowlist[idx];
        __syncthreads();
        xrow[t] = x[(size_t)row * D + t];
        __syncthreads();
        double lmin = 1e300;
        #pragma unroll
        for (int j = 0; j < 4; ++j) {
            const int c = 4 * t + j;
            const float* cp = codes + (size_t)c * D;
            double s = 0.0;
            for (int k = 0; k < D; k += 4) {
                float4 cv = *(const float4*)(cp + k);
                double d0 = (double)xrow[k+0] - (double)cv.x;
                double d1 = (double)xrow[k+1] - (double)cv.y;
                double d2 = (double)xrow[k+2] - (double)cv.z;
                double d3 = (double)xrow[k+3] - (double)cv.w;
                s += d0*d0 + d1*d1 + d2*d2 + d3*d3;
            }
            dbuf[c] = s;
            lmin = fmin(lmin, s);
        }
        rmin[t] = lmin;
        __syncthreads();
        for (int sft = 128; sft > 0; sft >>= 1) {
            if (t < sft) rmin[t] = fmin(rmin[t], rmin[t + sft]);
            __syncthreads();
        }
        const double dstar = rmin[0];
        int lidx = INT_MAX;
        #pragma unroll
        for (int j = 0; j < 4; ++j) {
            const int c = 4 * t + j;
            if (dbuf[c] < dstar + DELTA && c < lidx) lidx = c;
        }
        ridx[t] = lidx;
        __syncthreads();
        for (int sft = 128; sft > 0; sft >>= 1) {
            if (t < sft) ridx[t] = min(ridx[t], ridx[t + sft]);
            __syncthreads();
        }
        const int winc = ridx[0];
        if (t == 0) out_i[row] = (float)winc;
        if (t < 64) {
            float4 cv = ((const float4*)(codes + (size_t)winc * D))[t];
            ((float4*)(out_q + (size_t)row * D))[t] = cv;
        }
        __syncthreads();
    }
}

extern "C" void kernel_launch(void* const* d_in, const int* in_sizes, int n_in,
                              void* d_out, int out_size, void* d_ws, size_t ws_size,
                              hipStream_t stream) {
    const float* x     = (const float*)d_in[0];
    const float* codes = (const float*)d_in[1];
    const int N = in_sizes[0] / D;                 // 65536

    char* ws = (char*)d_ws;
    float*    cnorm   = (float*)ws;                       ws += C * 4;              // 4 KB
    float*    cnormb  = (float*)ws;                       ws += C * 4;              // 4 KB (biased +1024)
    float*    codes_t = (float*)ws;                       ws += (size_t)D * C * 4;  // 1 MB
    _Float16* codes_h = (_Float16*)ws;                    ws += (size_t)C * D * 2;  // 512 KB (tiled)
    int*      count1  = (int*)ws;                         ws += 16;
    int*      count2  = (int*)ws;                         ws += 16;
    int*      rowlist1 = (int*)ws;                        ws += (size_t)N * 4;
    int*      rowlist2 = (int*)ws;

    float* out_q = (float*)d_out;
    float* out_i = out_q + (size_t)N * D;

    prep<<<C / 4, 256, 0, stream>>>(codes, cnorm, cnormb, codes_h, codes_t, count1, count2);
    codebook_mfma<<<N / 64, 256, 0, stream>>>(x, codes_h, codes, cnormb,
                                              out_q, out_i, count1, rowlist1);
    rescue32<<<512, 256, 0, stream>>>(x, codes, codes_t, cnorm, count1, rowlist1,
                                      out_q, out_i, count2, rowlist2);
    rescue_exact<<<256, 256, 0, stream>>>(x, codes, count2, rowlist2, out_q, out_i);
}